// Round 2
// baseline (1290.265 us; speedup 1.0000x reference)
//
#include <hip/hip_runtime.h>
#include <hip/hip_bf16.h>

using bf16 = __hip_bfloat16;
typedef __attribute__((ext_vector_type(8))) short short8;
typedef __attribute__((ext_vector_type(4))) float f32x4;

static __device__ __forceinline__ bf16 f2b(float x) { return __float2bfloat16(x); }
static __device__ __forceinline__ float b2f(bf16 x) { return __bfloat162float(x); }

// ---------------- conv 3x3 SAME + relu (direct, weights in LDS) ----------------
__global__ void conv3x3_relu_kernel(const float* __restrict__ in, const float* __restrict__ w,
                                    const float* __restrict__ bias, float* __restrict__ out,
                                    int IC, int OC, int H, int W) {
  int oc = blockIdx.x;
  int b  = blockIdx.y;
  extern __shared__ float wl[];
  int nw = IC * 9;
  for (int i = threadIdx.x; i < nw; i += blockDim.x) wl[i] = w[(size_t)oc * nw + i];
  __syncthreads();
  float bv = bias[oc];
  int HW = H * W;
  const float* inb = in + (size_t)b * IC * HW;
  float* outp = out + ((size_t)b * OC + oc) * HW;
  for (int pix = threadIdx.x; pix < HW; pix += blockDim.x) {
    int y = pix / W, x = pix - y * W;
    float acc = bv;
    for (int ic = 0; ic < IC; ++ic) {
      const float* p = inb + (size_t)ic * HW;
      const float* wr = wl + ic * 9;
      #pragma unroll
      for (int ky = 0; ky < 3; ++ky) {
        int yy = y + ky - 1;
        if (yy < 0 || yy >= H) continue;
        const float* prow = p + yy * W;
        #pragma unroll
        for (int kx = 0; kx < 3; ++kx) {
          int xx = x + kx - 1;
          if (xx < 0 || xx >= W) continue;
          acc += prow[xx] * wr[ky * 3 + kx];
        }
      }
    }
    outp[pix] = fmaxf(acc, 0.f);
  }
}

// ---------------- 2x2 maxpool stride 2 ----------------
__global__ void maxpool2_kernel(const float* __restrict__ in, float* __restrict__ out,
                                int C, int H, int W) {
  int Ho = H >> 1, Wo = W >> 1;
  int total = C * Ho * Wo;
  int i = blockIdx.x * blockDim.x + threadIdx.x;
  if (i >= total) return;
  int c = i / (Ho * Wo);
  int r = i - c * (Ho * Wo);
  int y = r / Wo, x = r - y * Wo;
  const float* p = in + (size_t)c * H * W + (2 * y) * W + 2 * x;
  out[i] = fmaxf(fmaxf(p[0], p[1]), fmaxf(p[W], p[W + 1]));
}

// ---------------- u,v = F @ A, F @ Bm ; one block per (b,p) ----------------
__global__ void uv_kernel(const float* __restrict__ e4, const float* __restrict__ g1w,
                          float* __restrict__ u, float* __restrict__ v) {
  int b = blockIdx.x / 96, p = blockIdx.x - (blockIdx.x / 96) * 96;
  __shared__ float f[514];
  for (int c = threadIdx.x; c < 512; c += 256)
    f[c] = e4[((size_t)b * 512 + c) * 96 + p];
  if (threadIdx.x == 0) {
    f[512] = -1.0f + 2.0f * (float)(p / 8) / 11.0f;   // xc[p//8], from (12,8) meshgrid reshaped
    f[513] = -1.0f + 2.0f * (float)(p % 8) / 7.0f;    // yc[p%8]
  }
  __syncthreads();
  int n = threadIdx.x;
  float ua = 0.f, va = 0.f;
  for (int c = 0; c < 514; ++c) {
    float fv = f[c];
    ua += fv * g1w[(size_t)c * 256 + n];
    va += fv * g1w[(size_t)(514 + c) * 256 + n];
  }
  u[((size_t)b * 96 + p) * 256 + n] = ua;
  v[((size_t)b * 96 + p) * 256 + n] = va;
}

// ---------------- ws = sen @ Cm + g1_b ----------------
__global__ void ws_kernel(const float* __restrict__ sen, const float* __restrict__ g1w,
                          const float* __restrict__ g1b, float* __restrict__ wsv) {
  int b = blockIdx.x;
  __shared__ float s[384];
  for (int k = threadIdx.x; k < 384; k += 256) s[k] = sen[b * 384 + k];
  __syncthreads();
  int n = threadIdx.x;
  float a = g1b[n];
  for (int k = 0; k < 384; ++k) a += s[k] * g1w[(size_t)(1028 + k) * 256 + n];
  wsv[b * 256 + n] = a;
}

// ---------------- f32 -> bf16 transpose: in[R][C] -> out[C][R] ----------------
__global__ void transpose_f2b(const float* __restrict__ in, bf16* __restrict__ out,
                              int R, int C) {
  __shared__ bf16 t[32][33];
  int c0 = blockIdx.x * 32, r0 = blockIdx.y * 32;
  int x = threadIdx.x & 31, y = threadIdx.x >> 5;  // 32 x 8
  for (int yy = y; yy < 32; yy += 8) {
    int r = r0 + yy, c = c0 + x;
    if (r < R && c < C) t[yy][x] = f2b(in[(size_t)r * C + c]);
  }
  __syncthreads();
  for (int yy = y; yy < 32; yy += 8) {
    int c = c0 + yy, r = r0 + x;
    if (r < R && c < C) out[(size_t)c * R + r] = t[x][yy];
  }
}

// ---------------- GEMM2: h2[b,m,n] = relu(h1[b,m,:] @ W2 + b2), h1 formed on the fly ----------------
__launch_bounds__(256)
__global__ void gemm2_kernel(const float* __restrict__ u, const float* __restrict__ v,
                             const float* __restrict__ wsv, const bf16* __restrict__ w2t,
                             const float* __restrict__ g2b, bf16* __restrict__ h2) {
  int b = blockIdx.z;
  int m0 = blockIdx.y * 128;
  int n0 = blockIdx.x * 128;
  __shared__ __align__(16) short A_lds[128][72];
  __shared__ __align__(16) short B_lds[128][72];
  int tid = threadIdx.x;
  int wid = tid >> 6, lane = tid & 63;
  int quad = lane >> 4, l16 = lane & 15;
  int mw = (wid >> 1) * 64, nw = (wid & 1) * 64;
  f32x4 acc[4][4];
  #pragma unroll
  for (int i = 0; i < 4; ++i)
    #pragma unroll
    for (int j = 0; j < 4; ++j)
      #pragma unroll
      for (int e = 0; e < 4; ++e) acc[i][j][e] = 0.f;

  int row = tid >> 1, ks0 = (tid & 1) * 32;
  int m = m0 + row;
  int i_idx = m / 96, j_idx = m - i_idx * 96;
  const float* up = u + ((size_t)b * 96 + j_idx) * 256 + ks0;
  const float* vp = v + ((size_t)b * 96 + i_idx) * 256 + ks0;
  const float* wp = wsv + b * 256 + ks0;
  const bf16* bsrc = w2t + (size_t)(n0 + row) * 256 + ks0;

  for (int kc = 0; kc < 256; kc += 64) {
    if (kc) __syncthreads();
    {  // A staging: h1 = relu(u[j] + v[i] + ws), rounded to bf16
      short* dst = &A_lds[row][ks0];
      #pragma unroll
      for (int kk = 0; kk < 32; ++kk) {
        float h = up[kc + kk] + vp[kc + kk] + wp[kc + kk];
        bf16 hb = f2b(fmaxf(h, 0.f));
        dst[kk] = *(short*)&hb;
      }
    }
    {  // B staging: W2T rows are contiguous K
      const short8* s8 = (const short8*)(bsrc + kc);
      short8* d8 = (short8*)&B_lds[row][ks0];
      #pragma unroll
      for (int q = 0; q < 4; ++q) d8[q] = s8[q];
    }
    __syncthreads();
    #pragma unroll
    for (int ks = 0; ks < 64; ks += 32) {
      short8 af[4], bfr[4];
      #pragma unroll
      for (int mt = 0; mt < 4; ++mt)
        af[mt] = *(const short8*)&A_lds[mw + mt * 16 + l16][ks + quad * 8];
      #pragma unroll
      for (int nt = 0; nt < 4; ++nt)
        bfr[nt] = *(const short8*)&B_lds[nw + nt * 16 + l16][ks + quad * 8];
      #pragma unroll
      for (int mt = 0; mt < 4; ++mt)
        #pragma unroll
        for (int nt = 0; nt < 4; ++nt)
          acc[mt][nt] = __builtin_amdgcn_mfma_f32_16x16x32_bf16(af[mt], bfr[nt], acc[mt][nt], 0, 0, 0);
    }
  }
  bf16* h2b = h2 + (size_t)b * 9216 * 256;
  #pragma unroll
  for (int nt = 0; nt < 4; ++nt) {
    int gcol = n0 + nw + nt * 16 + l16;
    float bias = g2b[gcol];
    #pragma unroll
    for (int mt = 0; mt < 4; ++mt) {
      #pragma unroll
      for (int r = 0; r < 4; ++r) {
        int grow = m0 + mw + mt * 16 + quad * 4 + r;
        h2b[(size_t)grow * 256 + gcol] = f2b(fmaxf(acc[mt][nt][r] + bias, 0.f));
      }
    }
  }
}

// ---------------- GEMM3 + relu + pair-sum: phi[b,f] += sum_rows relu(h2 @ W3 + b3) ----------------
__launch_bounds__(256)
__global__ void gemm3_kernel(const bf16* __restrict__ h2, const bf16* __restrict__ w3t,
                             const float* __restrict__ g3b, float* __restrict__ phi) {
  int b = blockIdx.z;
  int m0 = blockIdx.y * 128;
  int n0 = blockIdx.x * 128;
  __shared__ __align__(16) short A_lds[128][72];
  __shared__ __align__(16) short B_lds[128][72];
  int tid = threadIdx.x;
  int wid = tid >> 6, lane = tid & 63;
  int quad = lane >> 4, l16 = lane & 15;
  int mw = (wid >> 1) * 64, nw = (wid & 1) * 64;
  f32x4 acc[4][4];
  #pragma unroll
  for (int i = 0; i < 4; ++i)
    #pragma unroll
    for (int j = 0; j < 4; ++j)
      #pragma unroll
      for (int e = 0; e < 4; ++e) acc[i][j][e] = 0.f;

  int row = tid >> 1, ks0 = (tid & 1) * 32;
  const bf16* asrc = h2 + ((size_t)b * 9216 + m0 + row) * 256 + ks0;
  const bf16* bsrc = w3t + (size_t)(n0 + row) * 256 + ks0;

  for (int kc = 0; kc < 256; kc += 64) {
    if (kc) __syncthreads();
    {
      const short8* sa = (const short8*)(asrc + kc);
      short8* da = (short8*)&A_lds[row][ks0];
      #pragma unroll
      for (int q = 0; q < 4; ++q) da[q] = sa[q];
      const short8* sb = (const short8*)(bsrc + kc);
      short8* db = (short8*)&B_lds[row][ks0];
      #pragma unroll
      for (int q = 0; q < 4; ++q) db[q] = sb[q];
    }
    __syncthreads();
    #pragma unroll
    for (int ks = 0; ks < 64; ks += 32) {
      short8 af[4], bfr[4];
      #pragma unroll
      for (int mt = 0; mt < 4; ++mt)
        af[mt] = *(const short8*)&A_lds[mw + mt * 16 + l16][ks + quad * 8];
      #pragma unroll
      for (int nt = 0; nt < 4; ++nt)
        bfr[nt] = *(const short8*)&B_lds[nw + nt * 16 + l16][ks + quad * 8];
      #pragma unroll
      for (int mt = 0; mt < 4; ++mt)
        #pragma unroll
        for (int nt = 0; nt < 4; ++nt)
          acc[mt][nt] = __builtin_amdgcn_mfma_f32_16x16x32_bf16(af[mt], bfr[nt], acc[mt][nt], 0, 0, 0);
    }
  }
  // epilogue: bias + relu + column sum over this block's 128 rows
  #pragma unroll
  for (int nt = 0; nt < 4; ++nt) {
    int gcol = n0 + nw + nt * 16 + l16;
    float bias = g3b[gcol];
    float s = 0.f;
    #pragma unroll
    for (int mt = 0; mt < 4; ++mt)
      #pragma unroll
      for (int r = 0; r < 4; ++r)
        s += fmaxf(acc[mt][nt][r] + bias, 0.f);
    s += __shfl_xor(s, 16, 64);
    s += __shfl_xor(s, 32, 64);
    if (quad == 0) atomicAdd(&phi[b * 3072 + gcol], s);
  }
}

__global__ void zero_kernel(float* __restrict__ p, int n) {
  int i = blockIdx.x * blockDim.x + threadIdx.x;
  if (i < n) p[i] = 0.f;
}

__global__ void store_out_kernel(const float* __restrict__ acc, float* __restrict__ out, int n) {
  int i = blockIdx.x * blockDim.x + threadIdx.x;
  if (i < n) out[i] = acc[i];
}

extern "C" void kernel_launch(void* const* d_in, const int* in_sizes, int n_in,
                              void* d_out, int out_size, void* d_ws, size_t ws_size,
                              hipStream_t stream) {
  const float* x   = (const float*)d_in[0];
  const float* sen = (const float*)d_in[1];
  const float* w1  = (const float*)d_in[2];
  const float* b1  = (const float*)d_in[3];
  const float* w2  = (const float*)d_in[4];
  const float* b2  = (const float*)d_in[5];
  const float* w3  = (const float*)d_in[6];
  const float* b3  = (const float*)d_in[7];
  const float* w4  = (const float*)d_in[8];
  const float* b4  = (const float*)d_in[9];
  const float* g1w = (const float*)d_in[10];
  const float* g1b = (const float*)d_in[11];
  const float* g2w = (const float*)d_in[12];
  const float* g2b = (const float*)d_in[13];
  const float* g3w = (const float*)d_in[14];
  const float* g3b = (const float*)d_in[15];
  float* out = (float*)d_out;

  char* wsp = (char*)d_ws;
  size_t off = 0;
  auto alloc = [&](size_t bytes) {
    char* p = wsp + off;
    off += (bytes + 255) & ~(size_t)255;
    return (void*)p;
  };
  float* e1  = (float*)alloc((size_t)4 * 64 * 64 * 96 * 4);
  float* p1  = (float*)alloc((size_t)4 * 64 * 32 * 48 * 4);
  float* e2  = (float*)alloc((size_t)4 * 128 * 32 * 48 * 4);
  float* p2  = (float*)alloc((size_t)4 * 128 * 16 * 24 * 4);
  float* e3  = (float*)alloc((size_t)4 * 256 * 16 * 24 * 4);
  float* p3  = (float*)alloc((size_t)4 * 256 * 8 * 12 * 4);
  float* e4  = (float*)alloc((size_t)4 * 512 * 96 * 4);
  float* u   = (float*)alloc((size_t)4 * 96 * 256 * 4);
  float* v   = (float*)alloc((size_t)4 * 96 * 256 * 4);
  float* wsv = (float*)alloc((size_t)4 * 256 * 4);
  bf16* w2t  = (bf16*)alloc((size_t)256 * 256 * 2);
  bf16* w3t  = (bf16*)alloc((size_t)3072 * 256 * 2);
  bf16* h2   = (bf16*)alloc((size_t)4 * 9216 * 256 * 2);
  float* phi = (float*)alloc((size_t)12288 * 4);

  // encoder
  conv3x3_relu_kernel<<<dim3(64, 4), 256, 27 * 4, stream>>>(x, w1, b1, e1, 3, 64, 64, 96);
  maxpool2_kernel<<<dim3(1536), 256, 0, stream>>>(e1, p1, 4 * 64, 64, 96);
  conv3x3_relu_kernel<<<dim3(128, 4), 256, 576 * 4, stream>>>(p1, w2, b2, e2, 64, 128, 32, 48);
  maxpool2_kernel<<<dim3(768), 256, 0, stream>>>(e2, p2, 4 * 128, 32, 48);
  conv3x3_relu_kernel<<<dim3(256, 4), 256, 1152 * 4, stream>>>(p2, w3, b3, e3, 128, 256, 16, 24);
  maxpool2_kernel<<<dim3(384), 256, 0, stream>>>(e3, p3, 4 * 256, 16, 24);
  conv3x3_relu_kernel<<<dim3(512, 4), 128, 2304 * 4, stream>>>(p3, w4, b4, e4, 256, 512, 8, 12);

  // head precompute
  uv_kernel<<<dim3(384), 256, 0, stream>>>(e4, g1w, u, v);
  ws_kernel<<<dim3(4), 256, 0, stream>>>(sen, g1w, g1b, wsv);
  transpose_f2b<<<dim3(8, 8), 256, 0, stream>>>(g2w, w2t, 256, 256);
  transpose_f2b<<<dim3(96, 8), 256, 0, stream>>>(g3w, w3t, 256, 3072);

  // big GEMMs
  gemm2_kernel<<<dim3(2, 72, 4), 256, 0, stream>>>(u, v, wsv, w2t, g2b, h2);
  zero_kernel<<<dim3(48), 256, 0, stream>>>(phi, 12288);
  gemm3_kernel<<<dim3(24, 72, 4), 256, 0, stream>>>(h2, w3t, g3b, phi);
  store_out_kernel<<<dim3(48), 256, 0, stream>>>(phi, out, 12288);
}

// Round 3
// 452.863 us; speedup vs baseline: 2.8491x; 2.8491x over previous
//
#include <hip/hip_runtime.h>
#include <hip/hip_bf16.h>

using bf16 = __hip_bfloat16;
typedef __attribute__((ext_vector_type(8))) short short8;
typedef __attribute__((ext_vector_type(4))) float f32x4;

static __device__ __forceinline__ bf16 f2b(float x) { return __float2bfloat16(x); }
static __device__ __forceinline__ float b2f(bf16 x) { return __bfloat162float(x); }

// ---------------- conv1: direct 3x3 SAME, NCHW f32 in -> NHWC bf16 out ----------------
// block = 256 threads = 4 pixels x 64 oc; grid = B*H*W/4
__global__ void conv1_nhwc_kernel(const float* __restrict__ x, const float* __restrict__ w,
                                  const float* __restrict__ bias, bf16* __restrict__ out) {
  const int H = 64, W = 96, HW = H * W;
  __shared__ float wl[27 * 64];  // wl[k*64+oc]
  int tid = threadIdx.x;
  for (int idx = tid; idx < 27 * 64; idx += 256) {
    int k = idx >> 6, oc_ = idx & 63;
    wl[idx] = w[oc_ * 27 + k];
  }
  __syncthreads();
  int oc = tid & 63;
  int pg = blockIdx.x * 4 + (tid >> 6);
  int b = pg / HW, pix = pg - b * HW;
  int y = pix / W, xx0 = pix - y * W;
  float acc = bias[oc];
  #pragma unroll
  for (int ic = 0; ic < 3; ++ic) {
    const float* xp = x + ((size_t)b * 3 + ic) * HW;
    #pragma unroll
    for (int ky = 0; ky < 3; ++ky) {
      int yy = y + ky - 1;
      if (yy < 0 || yy >= H) continue;
      #pragma unroll
      for (int kx = 0; kx < 3; ++kx) {
        int xx = xx0 + kx - 1;
        if (xx < 0 || xx >= W) continue;
        acc += xp[yy * W + xx] * wl[(ic * 9 + ky * 3 + kx) * 64 + oc];
      }
    }
  }
  out[(size_t)pg * 64 + oc] = f2b(fmaxf(acc, 0.f));
}

// ---------------- maxpool 2x2 stride 2, NHWC bf16 ----------------
__global__ void maxpool_nhwc_kernel(const bf16* __restrict__ in, bf16* __restrict__ out,
                                    int H, int W, int C) {
  int Ho = H >> 1, Wo = W >> 1;
  int total = 4 * Ho * Wo * C;
  int i = blockIdx.x * blockDim.x + threadIdx.x;
  if (i >= total) return;
  int c = i % C;
  int t = i / C;
  int xo = t % Wo; t /= Wo;
  int yo = t % Ho; int b = t / Ho;
  const bf16* p = in + (((size_t)(b * H + 2 * yo) * W) + 2 * xo) * C + c;
  float m = fmaxf(fmaxf(b2f(p[0]), b2f(p[C])),
                  fmaxf(b2f(p[(size_t)W * C]), b2f(p[(size_t)W * C + C])));
  out[i] = f2b(m);
}

// ---------------- weight reorder: [OC][IC][3][3] f32 -> [OC][9*IC] bf16 (tap-major, ic-contig) ----------------
__global__ void reorder_w_kernel(const float* __restrict__ src, bf16* __restrict__ dst,
                                 int OC, int IC) {
  int K = 9 * IC;
  int total = OC * K;
  int i = blockIdx.x * blockDim.x + threadIdx.x;
  if (i >= total) return;
  int oc = i / K, r = i - oc * K;
  int tap = r / IC, ic = r - tap * IC;
  dst[i] = f2b(src[((size_t)oc * IC + ic) * 9 + tap]);
}

// ---------------- im2col NHWC bf16: src [4][H][W][C] -> dst [4*H*W][9*C], short8 granularity ----------------
__global__ void im2col_nhwc_kernel(const bf16* __restrict__ src, bf16* __restrict__ dst,
                                   int H, int W, int C) {
  int n8 = C >> 3;
  int HW = H * W;
  int total = 4 * HW * 9 * n8;
  int i = blockIdx.x * blockDim.x + threadIdx.x;
  if (i >= total) return;
  int v = i % n8;
  int t = i / n8;
  int tap = t % 9;
  int row = t / 9;
  int b = row / HW, pix = row - b * HW;
  int y = pix / W, x = pix - y * W;
  int yy = y + tap / 3 - 1, xx = x + tap % 3 - 1;
  short8 val = {0, 0, 0, 0, 0, 0, 0, 0};
  if (yy >= 0 && yy < H && xx >= 0 && xx < W)
    val = ((const short8*)src)[((size_t)(b * H + yy) * W + xx) * n8 + v];
  ((short8*)dst)[(size_t)row * (9 * n8) + tap * n8 + v] = val;
}

// ---------------- generic GEMM + bias + relu: A[M][K]bf16, Wt[N][K]bf16 -> out[M][N] ----------------
// M%128==0, N%128==0, K%64==0. Writes bf16 if outb!=nullptr else f32 to outf.
__launch_bounds__(256)
__global__ void gemm_bias_relu_kernel(const bf16* __restrict__ A, const bf16* __restrict__ Wt,
                                      const float* __restrict__ bias, bf16* __restrict__ outb,
                                      float* __restrict__ outf, int K, int N) {
  int m0 = blockIdx.y * 128;
  int n0 = blockIdx.x * 128;
  __shared__ __align__(16) short A_lds[128][72];
  __shared__ __align__(16) short B_lds[128][72];
  int tid = threadIdx.x;
  int wid = tid >> 6, lane = tid & 63;
  int quad = lane >> 4, l16 = lane & 15;
  int mw = (wid >> 1) * 64, nw = (wid & 1) * 64;
  f32x4 acc[4][4];
  #pragma unroll
  for (int i = 0; i < 4; ++i)
    #pragma unroll
    for (int j = 0; j < 4; ++j)
      #pragma unroll
      for (int e = 0; e < 4; ++e) acc[i][j][e] = 0.f;

  int row = tid >> 1, ks0 = (tid & 1) * 32;
  const bf16* asrc = A + (size_t)(m0 + row) * K + ks0;
  const bf16* bsrc = Wt + (size_t)(n0 + row) * K + ks0;

  for (int kc = 0; kc < K; kc += 64) {
    if (kc) __syncthreads();
    {
      const short8* sa = (const short8*)(asrc + kc);
      short8* da = (short8*)&A_lds[row][ks0];
      #pragma unroll
      for (int q = 0; q < 4; ++q) da[q] = sa[q];
      const short8* sb = (const short8*)(bsrc + kc);
      short8* db = (short8*)&B_lds[row][ks0];
      #pragma unroll
      for (int q = 0; q < 4; ++q) db[q] = sb[q];
    }
    __syncthreads();
    #pragma unroll
    for (int ks = 0; ks < 64; ks += 32) {
      short8 af[4], bfr[4];
      #pragma unroll
      for (int mt = 0; mt < 4; ++mt)
        af[mt] = *(const short8*)&A_lds[mw + mt * 16 + l16][ks + quad * 8];
      #pragma unroll
      for (int nt = 0; nt < 4; ++nt)
        bfr[nt] = *(const short8*)&B_lds[nw + nt * 16 + l16][ks + quad * 8];
      #pragma unroll
      for (int mt = 0; mt < 4; ++mt)
        #pragma unroll
        for (int nt = 0; nt < 4; ++nt)
          acc[mt][nt] = __builtin_amdgcn_mfma_f32_16x16x32_bf16(af[mt], bfr[nt], acc[mt][nt], 0, 0, 0);
    }
  }
  #pragma unroll
  for (int nt = 0; nt < 4; ++nt) {
    int gcol = n0 + nw + nt * 16 + l16;
    float bv = bias[gcol];
    #pragma unroll
    for (int mt = 0; mt < 4; ++mt) {
      #pragma unroll
      for (int r = 0; r < 4; ++r) {
        int grow = m0 + mw + mt * 16 + quad * 4 + r;
        float val = fmaxf(acc[mt][nt][r] + bv, 0.f);
        if (outb) outb[(size_t)grow * N + gcol] = f2b(val);
        else      outf[(size_t)grow * N + gcol] = val;
      }
    }
  }
}

// ---------------- u,v = F @ A, F @ Bm ; F f32 [(b*96+p)][512] row-contiguous ----------------
__global__ void uv_kernel(const float* __restrict__ F, const float* __restrict__ g1w,
                          float* __restrict__ u, float* __restrict__ v) {
  int b = blockIdx.x / 96, p = blockIdx.x - (blockIdx.x / 96) * 96;
  __shared__ float f[514];
  for (int c = threadIdx.x; c < 512; c += 256)
    f[c] = F[(size_t)(b * 96 + p) * 512 + c];
  if (threadIdx.x == 0) {
    f[512] = -1.0f + 2.0f * (float)(p / 8) / 11.0f;   // xc[p//8]
    f[513] = -1.0f + 2.0f * (float)(p % 8) / 7.0f;    // yc[p%8]
  }
  __syncthreads();
  int n = threadIdx.x;
  float ua = 0.f, va = 0.f;
  for (int c = 0; c < 514; ++c) {
    float fv = f[c];
    ua += fv * g1w[(size_t)c * 256 + n];
    va += fv * g1w[(size_t)(514 + c) * 256 + n];
  }
  u[((size_t)b * 96 + p) * 256 + n] = ua;
  v[((size_t)b * 96 + p) * 256 + n] = va;
}

// ---------------- ws = sen @ Cm + g1_b ----------------
__global__ void ws_kernel(const float* __restrict__ sen, const float* __restrict__ g1w,
                          const float* __restrict__ g1b, float* __restrict__ wsv) {
  int b = blockIdx.x;
  __shared__ float s[384];
  for (int k = threadIdx.x; k < 384; k += 256) s[k] = sen[b * 384 + k];
  __syncthreads();
  int n = threadIdx.x;
  float a = g1b[n];
  for (int k = 0; k < 384; ++k) a += s[k] * g1w[(size_t)(1028 + k) * 256 + n];
  wsv[b * 256 + n] = a;
}

// ---------------- f32 -> bf16 transpose: in[R][C] -> out[C][R] ----------------
__global__ void transpose_f2b(const float* __restrict__ in, bf16* __restrict__ out,
                              int R, int C) {
  __shared__ bf16 t[32][33];
  int c0 = blockIdx.x * 32, r0 = blockIdx.y * 32;
  int x = threadIdx.x & 31, y = threadIdx.x >> 5;
  for (int yy = y; yy < 32; yy += 8) {
    int r = r0 + yy, c = c0 + x;
    if (r < R && c < C) t[yy][x] = f2b(in[(size_t)r * C + c]);
  }
  __syncthreads();
  for (int yy = y; yy < 32; yy += 8) {
    int c = c0 + yy, r = r0 + x;
    if (r < R && c < C) out[(size_t)c * R + r] = t[x][yy];
  }
}

// ---------------- GEMM2: h2 = relu(h1 @ W2 + b2), h1 formed on the fly ----------------
__launch_bounds__(256)
__global__ void gemm2_kernel(const float* __restrict__ u, const float* __restrict__ v,
                             const float* __restrict__ wsv, const bf16* __restrict__ w2t,
                             const float* __restrict__ g2b, bf16* __restrict__ h2) {
  int b = blockIdx.z;
  int m0 = blockIdx.y * 128;
  int n0 = blockIdx.x * 128;
  __shared__ __align__(16) short A_lds[128][72];
  __shared__ __align__(16) short B_lds[128][72];
  int tid = threadIdx.x;
  int wid = tid >> 6, lane = tid & 63;
  int quad = lane >> 4, l16 = lane & 15;
  int mw = (wid >> 1) * 64, nw = (wid & 1) * 64;
  f32x4 acc[4][4];
  #pragma unroll
  for (int i = 0; i < 4; ++i)
    #pragma unroll
    for (int j = 0; j < 4; ++j)
      #pragma unroll
      for (int e = 0; e < 4; ++e) acc[i][j][e] = 0.f;

  int row = tid >> 1, ks0 = (tid & 1) * 32;
  int m = m0 + row;
  int i_idx = m / 96, j_idx = m - i_idx * 96;
  const float* up = u + ((size_t)b * 96 + j_idx) * 256 + ks0;
  const float* vp = v + ((size_t)b * 96 + i_idx) * 256 + ks0;
  const float* wp = wsv + b * 256 + ks0;
  const bf16* bsrc = w2t + (size_t)(n0 + row) * 256 + ks0;

  for (int kc = 0; kc < 256; kc += 64) {
    if (kc) __syncthreads();
    {
      short* dst = &A_lds[row][ks0];
      #pragma unroll
      for (int kk = 0; kk < 32; ++kk) {
        float h = up[kc + kk] + vp[kc + kk] + wp[kc + kk];
        bf16 hb = f2b(fmaxf(h, 0.f));
        dst[kk] = *(short*)&hb;
      }
    }
    {
      const short8* s8 = (const short8*)(bsrc + kc);
      short8* d8 = (short8*)&B_lds[row][ks0];
      #pragma unroll
      for (int q = 0; q < 4; ++q) d8[q] = s8[q];
    }
    __syncthreads();
    #pragma unroll
    for (int ks = 0; ks < 64; ks += 32) {
      short8 af[4], bfr[4];
      #pragma unroll
      for (int mt = 0; mt < 4; ++mt)
        af[mt] = *(const short8*)&A_lds[mw + mt * 16 + l16][ks + quad * 8];
      #pragma unroll
      for (int nt = 0; nt < 4; ++nt)
        bfr[nt] = *(const short8*)&B_lds[nw + nt * 16 + l16][ks + quad * 8];
      #pragma unroll
      for (int mt = 0; mt < 4; ++mt)
        #pragma unroll
        for (int nt = 0; nt < 4; ++nt)
          acc[mt][nt] = __builtin_amdgcn_mfma_f32_16x16x32_bf16(af[mt], bfr[nt], acc[mt][nt], 0, 0, 0);
    }
  }
  bf16* h2b = h2 + (size_t)b * 9216 * 256;
  #pragma unroll
  for (int nt = 0; nt < 4; ++nt) {
    int gcol = n0 + nw + nt * 16 + l16;
    float bias = g2b[gcol];
    #pragma unroll
    for (int mt = 0; mt < 4; ++mt) {
      #pragma unroll
      for (int r = 0; r < 4; ++r) {
        int grow = m0 + mw + mt * 16 + quad * 4 + r;
        h2b[(size_t)grow * 256 + gcol] = f2b(fmaxf(acc[mt][nt][r] + bias, 0.f));
      }
    }
  }
}

// ---------------- GEMM3 + relu + pair-sum ----------------
__launch_bounds__(256)
__global__ void gemm3_kernel(const bf16* __restrict__ h2, const bf16* __restrict__ w3t,
                             const float* __restrict__ g3b, float* __restrict__ phi) {
  int b = blockIdx.z;
  int m0 = blockIdx.y * 128;
  int n0 = blockIdx.x * 128;
  __shared__ __align__(16) short A_lds[128][72];
  __shared__ __align__(16) short B_lds[128][72];
  int tid = threadIdx.x;
  int wid = tid >> 6, lane = tid & 63;
  int quad = lane >> 4, l16 = lane & 15;
  int mw = (wid >> 1) * 64, nw = (wid & 1) * 64;
  f32x4 acc[4][4];
  #pragma unroll
  for (int i = 0; i < 4; ++i)
    #pragma unroll
    for (int j = 0; j < 4; ++j)
      #pragma unroll
      for (int e = 0; e < 4; ++e) acc[i][j][e] = 0.f;

  int row = tid >> 1, ks0 = (tid & 1) * 32;
  const bf16* asrc = h2 + ((size_t)b * 9216 + m0 + row) * 256 + ks0;
  const bf16* bsrc = w3t + (size_t)(n0 + row) * 256 + ks0;

  for (int kc = 0; kc < 256; kc += 64) {
    if (kc) __syncthreads();
    {
      const short8* sa = (const short8*)(asrc + kc);
      short8* da = (short8*)&A_lds[row][ks0];
      #pragma unroll
      for (int q = 0; q < 4; ++q) da[q] = sa[q];
      const short8* sb = (const short8*)(bsrc + kc);
      short8* db = (short8*)&B_lds[row][ks0];
      #pragma unroll
      for (int q = 0; q < 4; ++q) db[q] = sb[q];
    }
    __syncthreads();
    #pragma unroll
    for (int ks = 0; ks < 64; ks += 32) {
      short8 af[4], bfr[4];
      #pragma unroll
      for (int mt = 0; mt < 4; ++mt)
        af[mt] = *(const short8*)&A_lds[mw + mt * 16 + l16][ks + quad * 8];
      #pragma unroll
      for (int nt = 0; nt < 4; ++nt)
        bfr[nt] = *(const short8*)&B_lds[nw + nt * 16 + l16][ks + quad * 8];
      #pragma unroll
      for (int mt = 0; mt < 4; ++mt)
        #pragma unroll
        for (int nt = 0; nt < 4; ++nt)
          acc[mt][nt] = __builtin_amdgcn_mfma_f32_16x16x32_bf16(af[mt], bfr[nt], acc[mt][nt], 0, 0, 0);
    }
  }
  #pragma unroll
  for (int nt = 0; nt < 4; ++nt) {
    int gcol = n0 + nw + nt * 16 + l16;
    float bias = g3b[gcol];
    float s = 0.f;
    #pragma unroll
    for (int mt = 0; mt < 4; ++mt)
      #pragma unroll
      for (int r = 0; r < 4; ++r)
        s += fmaxf(acc[mt][nt][r] + bias, 0.f);
    s += __shfl_xor(s, 16, 64);
    s += __shfl_xor(s, 32, 64);
    if (quad == 0) atomicAdd(&phi[b * 3072 + gcol], s);
  }
}

__global__ void zero_kernel(float* __restrict__ p, int n) {
  int i = blockIdx.x * blockDim.x + threadIdx.x;
  if (i < n) p[i] = 0.f;
}

__global__ void store_out_kernel(const float* __restrict__ acc, float* __restrict__ out, int n) {
  int i = blockIdx.x * blockDim.x + threadIdx.x;
  if (i < n) out[i] = acc[i];
}

extern "C" void kernel_launch(void* const* d_in, const int* in_sizes, int n_in,
                              void* d_out, int out_size, void* d_ws, size_t ws_size,
                              hipStream_t stream) {
  const float* x   = (const float*)d_in[0];
  const float* sen = (const float*)d_in[1];
  const float* w1  = (const float*)d_in[2];
  const float* b1  = (const float*)d_in[3];
  const float* w2  = (const float*)d_in[4];
  const float* b2  = (const float*)d_in[5];
  const float* w3  = (const float*)d_in[6];
  const float* b3  = (const float*)d_in[7];
  const float* w4  = (const float*)d_in[8];
  const float* b4  = (const float*)d_in[9];
  const float* g1w = (const float*)d_in[10];
  const float* g1b = (const float*)d_in[11];
  const float* g2w = (const float*)d_in[12];
  const float* g2b = (const float*)d_in[13];
  const float* g3w = (const float*)d_in[14];
  const float* g3b = (const float*)d_in[15];
  float* out = (float*)d_out;

  char* wsp = (char*)d_ws;
  size_t off = 0;
  auto alloc = [&](size_t bytes) {
    char* p = wsp + off;
    off += (bytes + 255) & ~(size_t)255;
    return (void*)p;
  };
  bf16* e1   = (bf16*)alloc((size_t)4 * 6144 * 64 * 2);    // NHWC 64x96x64
  bf16* p1   = (bf16*)alloc((size_t)4 * 1536 * 64 * 2);    // 32x48x64
  bf16* col2 = (bf16*)alloc((size_t)6144 * 576 * 2);
  bf16* e2   = (bf16*)alloc((size_t)6144 * 128 * 2);       // rows=(b,32x48), C=128
  bf16* p2   = (bf16*)alloc((size_t)4 * 384 * 128 * 2);    // 16x24x128
  bf16* col3 = (bf16*)alloc((size_t)1536 * 1152 * 2);
  bf16* e3   = (bf16*)alloc((size_t)1536 * 256 * 2);       // 16x24x256
  bf16* p3   = (bf16*)alloc((size_t)4 * 96 * 256 * 2);     // 8x12x256
  bf16* col4 = (bf16*)alloc((size_t)384 * 2304 * 2);
  float* F   = (float*)alloc((size_t)384 * 512 * 4);       // [(b,p)][512] f32
  bf16* w2r  = (bf16*)alloc((size_t)128 * 576 * 2);
  bf16* w3r  = (bf16*)alloc((size_t)256 * 1152 * 2);
  bf16* w4r  = (bf16*)alloc((size_t)512 * 2304 * 2);
  float* u   = (float*)alloc((size_t)4 * 96 * 256 * 4);
  float* v   = (float*)alloc((size_t)4 * 96 * 256 * 4);
  float* wsv = (float*)alloc((size_t)4 * 256 * 4);
  bf16* w2t  = (bf16*)alloc((size_t)256 * 256 * 2);
  bf16* w3t  = (bf16*)alloc((size_t)3072 * 256 * 2);
  bf16* h2   = (bf16*)alloc((size_t)4 * 9216 * 256 * 2);
  float* phi = (float*)alloc((size_t)12288 * 4);

  // weight prep (input-only deps)
  reorder_w_kernel<<<dim3(288), 256, 0, stream>>>(w2, w2r, 128, 64);
  reorder_w_kernel<<<dim3(1152), 256, 0, stream>>>(w3, w3r, 256, 128);
  reorder_w_kernel<<<dim3(4608), 256, 0, stream>>>(w4, w4r, 512, 256);
  transpose_f2b<<<dim3(8, 8), 256, 0, stream>>>(g2w, w2t, 256, 256);
  transpose_f2b<<<dim3(96, 8), 256, 0, stream>>>(g3w, w3t, 256, 3072);

  // encoder: conv1 direct, then implicit-GEMM convs
  conv1_nhwc_kernel<<<dim3(6144), 256, 0, stream>>>(x, w1, b1, e1);
  maxpool_nhwc_kernel<<<dim3(1536), 256, 0, stream>>>(e1, p1, 64, 96, 64);
  im2col_nhwc_kernel<<<dim3(1728), 256, 0, stream>>>(p1, col2, 32, 48, 64);
  gemm_bias_relu_kernel<<<dim3(1, 48), 256, 0, stream>>>(col2, w2r, b2, e2, nullptr, 576, 128);
  maxpool_nhwc_kernel<<<dim3(768), 256, 0, stream>>>(e2, p2, 32, 48, 128);
  im2col_nhwc_kernel<<<dim3(864), 256, 0, stream>>>(p2, col3, 16, 24, 128);
  gemm_bias_relu_kernel<<<dim3(2, 12), 256, 0, stream>>>(col3, w3r, b3, e3, nullptr, 1152, 256);
  maxpool_nhwc_kernel<<<dim3(384), 256, 0, stream>>>(e3, p3, 16, 24, 256);
  im2col_nhwc_kernel<<<dim3(432), 256, 0, stream>>>(p3, col4, 8, 12, 256);
  gemm_bias_relu_kernel<<<dim3(4, 3), 256, 0, stream>>>(col4, w4r, b4, nullptr, F, 2304, 512);

  // head
  uv_kernel<<<dim3(384), 256, 0, stream>>>(F, g1w, u, v);
  ws_kernel<<<dim3(4), 256, 0, stream>>>(sen, g1w, g1b, wsv);
  gemm2_kernel<<<dim3(2, 72, 4), 256, 0, stream>>>(u, v, wsv, w2t, g2b, h2);
  zero_kernel<<<dim3(48), 256, 0, stream>>>(phi, 12288);
  gemm3_kernel<<<dim3(24, 72, 4), 256, 0, stream>>>(h2, w3t, g3b, phi);
  store_out_kernel<<<dim3(48), 256, 0, stream>>>(phi, out, 12288);
}

// Round 4
// 346.799 us; speedup vs baseline: 3.7205x; 1.3058x over previous
//
#include <hip/hip_runtime.h>
#include <hip/hip_bf16.h>

using bf16 = __hip_bfloat16;
typedef __attribute__((ext_vector_type(8))) short short8;
typedef __attribute__((ext_vector_type(4))) float f32x4;

static __device__ __forceinline__ bf16 f2b(float x) { return __float2bfloat16(x); }
static __device__ __forceinline__ float b2f(bf16 x) { return __bfloat162float(x); }

// async global->LDS, 16B per lane. HW semantics: LDS dest = wave-uniform base + lane*16.
static __device__ __forceinline__ void gload_lds16(const void* g, void* l) {
  auto gp = (const __attribute__((address_space(1))) unsigned int*)g;
  auto lp = (__attribute__((address_space(3))) unsigned int*)l;
  __builtin_amdgcn_global_load_lds(gp, lp, 16, 0, 0);
}

// ---------------- conv1: direct 3x3 SAME, NCHW f32 in -> NHWC bf16 out ----------------
__global__ void conv1_nhwc_kernel(const float* __restrict__ x, const float* __restrict__ w,
                                  const float* __restrict__ bias, bf16* __restrict__ out) {
  const int H = 64, W = 96, HW = H * W;
  __shared__ float wl[27 * 64];
  int tid = threadIdx.x;
  for (int idx = tid; idx < 27 * 64; idx += 256) {
    int k = idx >> 6, oc_ = idx & 63;
    wl[idx] = w[oc_ * 27 + k];
  }
  __syncthreads();
  int oc = tid & 63;
  int pg = blockIdx.x * 4 + (tid >> 6);
  int b = pg / HW, pix = pg - b * HW;
  int y = pix / W, xx0 = pix - y * W;
  float acc = bias[oc];
  #pragma unroll
  for (int ic = 0; ic < 3; ++ic) {
    const float* xp = x + ((size_t)b * 3 + ic) * HW;
    #pragma unroll
    for (int ky = 0; ky < 3; ++ky) {
      int yy = y + ky - 1;
      if (yy < 0 || yy >= H) continue;
      #pragma unroll
      for (int kx = 0; kx < 3; ++kx) {
        int xx = xx0 + kx - 1;
        if (xx < 0 || xx >= W) continue;
        acc += xp[yy * W + xx] * wl[(ic * 9 + ky * 3 + kx) * 64 + oc];
      }
    }
  }
  out[(size_t)pg * 64 + oc] = f2b(fmaxf(acc, 0.f));
}

// ---------------- fused maxpool2 + im2col: src NHWC [4][H][W][C] (post-relu) -> col [4*Hp*Wp][9*C] ----------------
__global__ void pool_im2col_kernel(const bf16* __restrict__ src, bf16* __restrict__ dst,
                                   int H, int W, int C) {
  int n8 = C >> 3, Hp = H >> 1, Wp = W >> 1;
  int total = 4 * Hp * Wp * 9 * n8;
  int i = blockIdx.x * blockDim.x + threadIdx.x;
  if (i >= total) return;
  int v = i % n8;
  int t = i / n8;
  int tap = t % 9;
  int row = t / 9;
  int HWp = Hp * Wp;
  int b = row / HWp, pix = row - b * HWp;
  int yp = pix / Wp, xp = pix - yp * Wp;
  int yy = yp + tap / 3 - 1, xx = xp + tap % 3 - 1;
  short8 outv = {0, 0, 0, 0, 0, 0, 0, 0};
  if (yy >= 0 && yy < Hp && xx >= 0 && xx < Wp) {
    const short8* s = (const short8*)src;
    size_t base = ((size_t)(b * H + 2 * yy) * W + 2 * xx) * n8 + v;
    short8 a0 = s[base], a1 = s[base + n8];
    short8 a2 = s[base + (size_t)W * n8], a3 = s[base + (size_t)W * n8 + n8];
    // post-relu bf16 >= 0: integer max == float max on raw bits
    #pragma unroll
    for (int e = 0; e < 8; ++e) {
      unsigned short m0 = (unsigned short)a0[e], m1 = (unsigned short)a1[e];
      unsigned short m2 = (unsigned short)a2[e], m3 = (unsigned short)a3[e];
      unsigned short m = m0 > m1 ? m0 : m1;
      unsigned short n = m2 > m3 ? m2 : m3;
      outv[e] = (short)(m > n ? m : n);
    }
  }
  ((short8*)dst)[(size_t)row * (9 * n8) + tap * n8 + v] = outv;
}

// ---------------- prep: weight reorders + wuv build + phi zero + Fe coord/pad, one flat kernel ----------------
__global__ void prep_kernel(const float* __restrict__ w2, const float* __restrict__ w3,
                            const float* __restrict__ w4, const float* __restrict__ g1w,
                            float* __restrict__ phi, bf16* __restrict__ w2r,
                            bf16* __restrict__ w3r, bf16* __restrict__ w4r,
                            bf16* __restrict__ wuv, bf16* __restrict__ Fe) {
  const int S1 = 73728, S2 = S1 + 294912, S3 = S2 + 1179648, S4 = S3 + 294912,
            S5 = S4 + 12288, S6 = S5 + 24576;
  int i = blockIdx.x * 256 + threadIdx.x;
  if (i < S1) {  // w2: OC=128 IC=64
    int j = i, K = 576, IC = 64;
    int oc = j / K, r = j - oc * K, tap = r / IC, ic = r - tap * IC;
    w2r[j] = f2b(w2[((size_t)oc * IC + ic) * 9 + tap]);
  } else if (i < S2) {  // w3: OC=256 IC=128
    int j = i - S1, K = 1152, IC = 128;
    int oc = j / K, r = j - oc * K, tap = r / IC, ic = r - tap * IC;
    w3r[j] = f2b(w3[((size_t)oc * IC + ic) * 9 + tap]);
  } else if (i < S3) {  // w4: OC=512 IC=256
    int j = i - S2, K = 2304, IC = 256;
    int oc = j / K, r = j - oc * K, tap = r / IC, ic = r - tap * IC;
    w4r[j] = f2b(w4[((size_t)oc * IC + ic) * 9 + tap]);
  } else if (i < S4) {  // wuv[512][576]
    int j = i - S3;
    int n = j / 576, c = j - n * 576;
    float val = 0.f;
    if (c < 514) val = (n < 256) ? g1w[(size_t)c * 256 + n] : g1w[(size_t)(514 + c) * 256 + (n - 256)];
    wuv[j] = f2b(val);
  } else if (i < S5) {  // phi zero
    phi[i - S4] = 0.f;
  } else if (i < S6) {  // Fe cols 512..575 (coords + zero pad)
    int j = i - S5;
    int r = j >> 6, cc = j & 63;
    int p = r % 96;
    float val = 0.f;
    if (cc == 0) val = -1.0f + 2.0f * (float)(p / 8) / 11.0f;   // xc[p//8]
    else if (cc == 1) val = -1.0f + 2.0f * (float)(p % 8) / 7.0f;  // yc[p%8]
    Fe[(size_t)r * 576 + 512 + cc] = f2b(val);
  }
}

// ---------------- f32 -> bf16 transpose: in[R][C] -> out[C][R] ----------------
__global__ void transpose_f2b(const float* __restrict__ in, bf16* __restrict__ out,
                              int R, int C) {
  __shared__ bf16 t[32][33];
  int c0 = blockIdx.x * 32, r0 = blockIdx.y * 32;
  int x = threadIdx.x & 31, y = threadIdx.x >> 5;
  for (int yy = y; yy < 32; yy += 8) {
    int r = r0 + yy, c = c0 + x;
    if (r < R && c < C) t[yy][x] = f2b(in[(size_t)r * C + c]);
  }
  __syncthreads();
  for (int yy = y; yy < 32; yy += 8) {
    int c = c0 + yy, r = r0 + x;
    if (r < R && c < C) out[(size_t)c * R + r] = t[x][yy];
  }
}

// ---------------- ws = sen @ Cm + g1_b ----------------
__global__ void ws_kernel(const float* __restrict__ sen, const float* __restrict__ g1w,
                          const float* __restrict__ g1b, float* __restrict__ wsv) {
  int b = blockIdx.x;
  __shared__ float s[384];
  for (int k = threadIdx.x; k < 384; k += 256) s[k] = sen[b * 384 + k];
  __syncthreads();
  int n = threadIdx.x;
  float a = g1b[n];
  for (int k = 0; k < 384; ++k) a += s[k] * g1w[(size_t)(1028 + k) * 256 + n];
  wsv[b * 256 + n] = a;
}

// ---------------- generic GEMM, global_load_lds staging + XOR-swizzled LDS ----------------
// A[M][K]bf16 row-major, Wt[N][K]bf16. mode 0: outb=relu(acc+bias) bf16; mode 2: outf=acc f32.
__launch_bounds__(256)
__global__ void gemm_glds_kernel(const bf16* __restrict__ A, const bf16* __restrict__ Wt,
                                 const float* __restrict__ bias, bf16* __restrict__ outb,
                                 float* __restrict__ outf, int K, int ldout, int mode) {
  int m0 = blockIdx.y * 128, n0 = blockIdx.x * 128;
  __shared__ __align__(16) short A_lds[128 * 64];
  __shared__ __align__(16) short B_lds[128 * 64];
  int tid = threadIdx.x, w = tid >> 6, l = tid & 63;
  int quad = l >> 4, l16 = l & 15;
  int mw = (w >> 1) * 64, nw = (w & 1) * 64;
  f32x4 acc[4][4];
  #pragma unroll
  for (int i = 0; i < 4; ++i)
    #pragma unroll
    for (int j = 0; j < 4; ++j)
      #pragma unroll
      for (int e = 0; e < 4; ++e) acc[i][j][e] = 0.f;

  // staging: wave w covers rows w*32 + i*8 + (l>>3), i=0..3; lane chunk p=l&7 holds
  // source chunk c = p ^ (row&7); row&7 == l>>3 here.
  int lrow = l >> 3;
  int c_sw = (l & 7) ^ lrow;
  const bf16* ag = A + (size_t)(m0 + w * 32 + lrow) * K + c_sw * 8;
  const bf16* bg = Wt + (size_t)(n0 + w * 32 + lrow) * K + c_sw * 8;
  short* al = A_lds + ((size_t)w * 256 + l) * 8;
  short* bl = B_lds + ((size_t)w * 256 + l) * 8;

  for (int kc = 0; kc < K; kc += 64) {
    if (kc) __syncthreads();
    #pragma unroll
    for (int i = 0; i < 4; ++i) {
      gload_lds16(ag + kc + (size_t)i * 8 * K, al + i * 512);
      gload_lds16(bg + kc + (size_t)i * 8 * K, bl + i * 512);
    }
    __syncthreads();
    #pragma unroll
    for (int ks = 0; ks < 64; ks += 32) {
      int cb = (ks >> 3) + quad;
      short8 af[4], bfr[4];
      #pragma unroll
      for (int mt = 0; mt < 4; ++mt) {
        int row = mw + mt * 16 + l16;
        af[mt] = *(const short8*)&A_lds[row * 64 + (cb ^ (row & 7)) * 8];
      }
      #pragma unroll
      for (int nt = 0; nt < 4; ++nt) {
        int row = nw + nt * 16 + l16;
        bfr[nt] = *(const short8*)&B_lds[row * 64 + (cb ^ (row & 7)) * 8];
      }
      #pragma unroll
      for (int mt = 0; mt < 4; ++mt)
        #pragma unroll
        for (int nt = 0; nt < 4; ++nt)
          acc[mt][nt] = __builtin_amdgcn_mfma_f32_16x16x32_bf16(af[mt], bfr[nt], acc[mt][nt], 0, 0, 0);
    }
  }
  #pragma unroll
  for (int nt = 0; nt < 4; ++nt) {
    int gcol = n0 + nw + nt * 16 + l16;
    float bv = (mode == 0) ? bias[gcol] : 0.f;
    #pragma unroll
    for (int mt = 0; mt < 4; ++mt) {
      #pragma unroll
      for (int r = 0; r < 4; ++r) {
        int grow = m0 + mw + mt * 16 + quad * 4 + r;
        if (mode == 0) outb[(size_t)grow * ldout + gcol] = f2b(fmaxf(acc[mt][nt][r] + bv, 0.f));
        else           outf[(size_t)grow * ldout + gcol] = acc[mt][nt][r];
      }
    }
  }
}

// ---------------- GEMM2: h2 = relu(h1 @ W2 + b2), h1 formed on the fly ----------------
__launch_bounds__(256)
__global__ void gemm2_kernel(const float* __restrict__ uvb, const float* __restrict__ wsv,
                             const bf16* __restrict__ w2t, const float* __restrict__ g2b,
                             bf16* __restrict__ h2) {
  int b = blockIdx.z;
  int m0 = blockIdx.y * 128;
  int n0 = blockIdx.x * 128;
  __shared__ __align__(16) short A_lds[128][72];
  __shared__ __align__(16) short B_lds[128][72];
  int tid = threadIdx.x;
  int wid = tid >> 6, lane = tid & 63;
  int quad = lane >> 4, l16 = lane & 15;
  int mw = (wid >> 1) * 64, nw = (wid & 1) * 64;
  f32x4 acc[4][4];
  #pragma unroll
  for (int i = 0; i < 4; ++i)
    #pragma unroll
    for (int j = 0; j < 4; ++j)
      #pragma unroll
      for (int e = 0; e < 4; ++e) acc[i][j][e] = 0.f;

  int row = tid >> 1, ks0 = (tid & 1) * 32;
  int m = m0 + row;
  int i_idx = m / 96, j_idx = m - i_idx * 96;
  const float* up = uvb + ((size_t)b * 96 + j_idx) * 512 + ks0;
  const float* vp = uvb + ((size_t)b * 96 + i_idx) * 512 + 256 + ks0;
  const float* wp = wsv + b * 256 + ks0;
  const bf16* bsrc = w2t + (size_t)(n0 + row) * 256 + ks0;

  for (int kc = 0; kc < 256; kc += 64) {
    if (kc) __syncthreads();
    {
      short* dst = &A_lds[row][ks0];
      #pragma unroll
      for (int kk = 0; kk < 32; ++kk) {
        float h = up[kc + kk] + vp[kc + kk] + wp[kc + kk];
        bf16 hb = f2b(fmaxf(h, 0.f));
        dst[kk] = *(short*)&hb;
      }
    }
    {
      const short8* s8 = (const short8*)(bsrc + kc);
      short8* d8 = (short8*)&B_lds[row][ks0];
      #pragma unroll
      for (int q = 0; q < 4; ++q) d8[q] = s8[q];
    }
    __syncthreads();
    #pragma unroll
    for (int ks = 0; ks < 64; ks += 32) {
      short8 af[4], bfr[4];
      #pragma unroll
      for (int mt = 0; mt < 4; ++mt)
        af[mt] = *(const short8*)&A_lds[mw + mt * 16 + l16][ks + quad * 8];
      #pragma unroll
      for (int nt = 0; nt < 4; ++nt)
        bfr[nt] = *(const short8*)&B_lds[nw + nt * 16 + l16][ks + quad * 8];
      #pragma unroll
      for (int mt = 0; mt < 4; ++mt)
        #pragma unroll
        for (int nt = 0; nt < 4; ++nt)
          acc[mt][nt] = __builtin_amdgcn_mfma_f32_16x16x32_bf16(af[mt], bfr[nt], acc[mt][nt], 0, 0, 0);
    }
  }
  bf16* h2b = h2 + (size_t)b * 9216 * 256;
  #pragma unroll
  for (int nt = 0; nt < 4; ++nt) {
    int gcol = n0 + nw + nt * 16 + l16;
    float bias = g2b[gcol];
    #pragma unroll
    for (int mt = 0; mt < 4; ++mt) {
      #pragma unroll
      for (int r = 0; r < 4; ++r) {
        int grow = m0 + mw + mt * 16 + quad * 4 + r;
        h2b[(size_t)grow * 256 + gcol] = f2b(fmaxf(acc[mt][nt][r] + bias, 0.f));
      }
    }
  }
}

// ---------------- GEMM3 + relu + pair-sum, global_load_lds staging ----------------
__launch_bounds__(256)
__global__ void gemm3_kernel(const bf16* __restrict__ h2, const bf16* __restrict__ w3t,
                             const float* __restrict__ g3b, float* __restrict__ phi) {
  int b = blockIdx.z;
  int m0 = blockIdx.y * 128;
  int n0 = blockIdx.x * 128;
  __shared__ __align__(16) short A_lds[128 * 64];
  __shared__ __align__(16) short B_lds[128 * 64];
  int tid = threadIdx.x, w = tid >> 6, l = tid & 63;
  int quad = l >> 4, l16 = l & 15;
  int mw = (w >> 1) * 64, nw = (w & 1) * 64;
  f32x4 acc[4][4];
  #pragma unroll
  for (int i = 0; i < 4; ++i)
    #pragma unroll
    for (int j = 0; j < 4; ++j)
      #pragma unroll
      for (int e = 0; e < 4; ++e) acc[i][j][e] = 0.f;

  const int K = 256;
  int lrow = l >> 3;
  int c_sw = (l & 7) ^ lrow;
  const bf16* ag = h2 + (size_t)(b * 9216 + m0 + w * 32 + lrow) * K + c_sw * 8;
  const bf16* bg = w3t + (size_t)(n0 + w * 32 + lrow) * K + c_sw * 8;
  short* al = A_lds + ((size_t)w * 256 + l) * 8;
  short* bl = B_lds + ((size_t)w * 256 + l) * 8;

  for (int kc = 0; kc < K; kc += 64) {
    if (kc) __syncthreads();
    #pragma unroll
    for (int i = 0; i < 4; ++i) {
      gload_lds16(ag + kc + (size_t)i * 8 * K, al + i * 512);
      gload_lds16(bg + kc + (size_t)i * 8 * K, bl + i * 512);
    }
    __syncthreads();
    #pragma unroll
    for (int ks = 0; ks < 64; ks += 32) {
      int cb = (ks >> 3) + quad;
      short8 af[4], bfr[4];
      #pragma unroll
      for (int mt = 0; mt < 4; ++mt) {
        int row = mw + mt * 16 + l16;
        af[mt] = *(const short8*)&A_lds[row * 64 + (cb ^ (row & 7)) * 8];
      }
      #pragma unroll
      for (int nt = 0; nt < 4; ++nt) {
        int row = nw + nt * 16 + l16;
        bfr[nt] = *(const short8*)&B_lds[row * 64 + (cb ^ (row & 7)) * 8];
      }
      #pragma unroll
      for (int mt = 0; mt < 4; ++mt)
        #pragma unroll
        for (int nt = 0; nt < 4; ++nt)
          acc[mt][nt] = __builtin_amdgcn_mfma_f32_16x16x32_bf16(af[mt], bfr[nt], acc[mt][nt], 0, 0, 0);
    }
  }
  #pragma unroll
  for (int nt = 0; nt < 4; ++nt) {
    int gcol = n0 + nw + nt * 16 + l16;
    float bias = g3b[gcol];
    float s = 0.f;
    #pragma unroll
    for (int mt = 0; mt < 4; ++mt)
      #pragma unroll
      for (int r = 0; r < 4; ++r)
        s += fmaxf(acc[mt][nt][r] + bias, 0.f);
    s += __shfl_xor(s, 16, 64);
    s += __shfl_xor(s, 32, 64);
    if (quad == 0) atomicAdd(&phi[b * 3072 + gcol], s);
  }
}

__global__ void store_out_kernel(const float* __restrict__ acc, float* __restrict__ out, int n) {
  int i = blockIdx.x * blockDim.x + threadIdx.x;
  if (i < n) out[i] = acc[i];
}

extern "C" void kernel_launch(void* const* d_in, const int* in_sizes, int n_in,
                              void* d_out, int out_size, void* d_ws, size_t ws_size,
                              hipStream_t stream) {
  const float* x   = (const float*)d_in[0];
  const float* sen = (const float*)d_in[1];
  const float* w1  = (const float*)d_in[2];
  const float* b1  = (const float*)d_in[3];
  const float* w2  = (const float*)d_in[4];
  const float* b2  = (const float*)d_in[5];
  const float* w3  = (const float*)d_in[6];
  const float* b3  = (const float*)d_in[7];
  const float* w4  = (const float*)d_in[8];
  const float* b4  = (const float*)d_in[9];
  const float* g1w = (const float*)d_in[10];
  const float* g1b = (const float*)d_in[11];
  const float* g2w = (const float*)d_in[12];
  const float* g2b = (const float*)d_in[13];
  const float* g3w = (const float*)d_in[14];
  const float* g3b = (const float*)d_in[15];
  float* out = (float*)d_out;

  char* wsp = (char*)d_ws;
  size_t off = 0;
  auto alloc = [&](size_t bytes) {
    char* p = wsp + off;
    off += (bytes + 255) & ~(size_t)255;
    return (void*)p;
  };
  bf16* e1   = (bf16*)alloc((size_t)4 * 6144 * 64 * 2);    // NHWC 64x96x64
  bf16* col2 = (bf16*)alloc((size_t)6144 * 576 * 2);
  bf16* e2   = (bf16*)alloc((size_t)6144 * 128 * 2);       // 32x48x128
  bf16* col3 = (bf16*)alloc((size_t)1536 * 1152 * 2);
  bf16* e3   = (bf16*)alloc((size_t)1536 * 256 * 2);       // 16x24x256
  bf16* col4 = (bf16*)alloc((size_t)384 * 2304 * 2);
  bf16* Fe   = (bf16*)alloc((size_t)384 * 576 * 2);        // [F | coords | pad]
  bf16* wuv  = (bf16*)alloc((size_t)512 * 576 * 2);        // [A^T ; Bm^T] K-padded
  float* uvb = (float*)alloc((size_t)384 * 512 * 4);       // [u | v] per (b,p)
  float* wsv = (float*)alloc((size_t)4 * 256 * 4);
  bf16* w2r  = (bf16*)alloc((size_t)128 * 576 * 2);
  bf16* w3r  = (bf16*)alloc((size_t)256 * 1152 * 2);
  bf16* w4r  = (bf16*)alloc((size_t)512 * 2304 * 2);
  bf16* w2t  = (bf16*)alloc((size_t)256 * 256 * 2);
  bf16* w3t  = (bf16*)alloc((size_t)3072 * 256 * 2);
  bf16* h2   = (bf16*)alloc((size_t)4 * 9216 * 256 * 2);
  float* phi = (float*)alloc((size_t)12288 * 4);

  // prep: weight reorders, wuv, phi zero, Fe coords (input-only deps)
  prep_kernel<<<dim3(7344), 256, 0, stream>>>(w2, w3, w4, g1w, phi, w2r, w3r, w4r, wuv, Fe);
  transpose_f2b<<<dim3(8, 8), 256, 0, stream>>>(g2w, w2t, 256, 256);
  transpose_f2b<<<dim3(96, 8), 256, 0, stream>>>(g3w, w3t, 256, 3072);
  ws_kernel<<<dim3(4), 256, 0, stream>>>(sen, g1w, g1b, wsv);

  // encoder
  conv1_nhwc_kernel<<<dim3(6144), 256, 0, stream>>>(x, w1, b1, e1);
  pool_im2col_kernel<<<dim3(1728), 256, 0, stream>>>(e1, col2, 64, 96, 64);
  gemm_glds_kernel<<<dim3(1, 48), 256, 0, stream>>>(col2, w2r, b2, e2, nullptr, 576, 128, 0);
  pool_im2col_kernel<<<dim3(864), 256, 0, stream>>>(e2, col3, 32, 48, 128);
  gemm_glds_kernel<<<dim3(2, 12), 256, 0, stream>>>(col3, w3r, b3, e3, nullptr, 1152, 256, 0);
  pool_im2col_kernel<<<dim3(432), 256, 0, stream>>>(e3, col4, 16, 24, 256);
  gemm_glds_kernel<<<dim3(4, 3), 256, 0, stream>>>(col4, w4r, b4, Fe, nullptr, 2304, 576, 0);

  // head: u,v via MFMA GEMM (M=384,N=512,K=576)
  gemm_glds_kernel<<<dim3(4, 3), 256, 0, stream>>>(Fe, wuv, nullptr, nullptr, uvb, 576, 512, 2);
  gemm2_kernel<<<dim3(2, 72, 4), 256, 0, stream>>>(uvb, wsv, w2t, g2b, h2);
  gemm3_kernel<<<dim3(24, 72, 4), 256, 0, stream>>>(h2, w3t, g3b, phi);
  store_out_kernel<<<dim3(48), 256, 0, stream>>>(phi, out, 12288);
}

// Round 5
// 283.145 us; speedup vs baseline: 4.5569x; 1.2248x over previous
//
#include <hip/hip_runtime.h>
#include <hip/hip_bf16.h>

using bf16 = __hip_bfloat16;
typedef __attribute__((ext_vector_type(8))) short short8;
typedef __attribute__((ext_vector_type(4))) float f32x4;

static __device__ __forceinline__ bf16 f2b(float x) { return __float2bfloat16(x); }
static __device__ __forceinline__ float b2f(bf16 x) { return __bfloat162float(x); }
static __device__ __forceinline__ short fb(float x) {
  bf16 h = __float2bfloat16(fmaxf(x, 0.f));
  return *(short*)&h;
}

// async global->LDS, 16B per lane (LDS dest = wave-uniform base + lane*16).
static __device__ __forceinline__ void gload_lds16(const void* g, void* l) {
  auto gp = (const __attribute__((address_space(1))) unsigned int*)g;
  auto lp = (__attribute__((address_space(3))) unsigned int*)l;
  __builtin_amdgcn_global_load_lds(gp, lp, 16, 0, 0);
}

// ---------------- conv1: direct 3x3 SAME, NCHW f32 in -> NHWC bf16 out ----------------
__global__ void conv1_nhwc_kernel(const float* __restrict__ x, const float* __restrict__ w,
                                  const float* __restrict__ bias, bf16* __restrict__ out) {
  const int H = 64, W = 96, HW = H * W;
  __shared__ float wl[27 * 64];
  int tid = threadIdx.x;
  for (int idx = tid; idx < 27 * 64; idx += 256) {
    int k = idx >> 6, oc_ = idx & 63;
    wl[idx] = w[oc_ * 27 + k];
  }
  __syncthreads();
  int oc = tid & 63;
  int pg = blockIdx.x * 4 + (tid >> 6);
  int b = pg / HW, pix = pg - b * HW;
  int y = pix / W, xx0 = pix - y * W;
  float acc = bias[oc];
  #pragma unroll
  for (int ic = 0; ic < 3; ++ic) {
    const float* xp = x + ((size_t)b * 3 + ic) * HW;
    #pragma unroll
    for (int ky = 0; ky < 3; ++ky) {
      int yy = y + ky - 1;
      if (yy < 0 || yy >= H) continue;
      #pragma unroll
      for (int kx = 0; kx < 3; ++kx) {
        int xx = xx0 + kx - 1;
        if (xx < 0 || xx >= W) continue;
        acc += xp[yy * W + xx] * wl[(ic * 9 + ky * 3 + kx) * 64 + oc];
      }
    }
  }
  out[(size_t)pg * 64 + oc] = f2b(fmaxf(acc, 0.f));
}

// ---------------- fused maxpool2 + im2col ----------------
__global__ void pool_im2col_kernel(const bf16* __restrict__ src, bf16* __restrict__ dst,
                                   int H, int W, int C) {
  int n8 = C >> 3, Hp = H >> 1, Wp = W >> 1;
  int total = 4 * Hp * Wp * 9 * n8;
  int i = blockIdx.x * blockDim.x + threadIdx.x;
  if (i >= total) return;
  int v = i % n8;
  int t = i / n8;
  int tap = t % 9;
  int row = t / 9;
  int HWp = Hp * Wp;
  int b = row / HWp, pix = row - b * HWp;
  int yp = pix / Wp, xp = pix - yp * Wp;
  int yy = yp + tap / 3 - 1, xx = xp + tap % 3 - 1;
  short8 outv = {0, 0, 0, 0, 0, 0, 0, 0};
  if (yy >= 0 && yy < Hp && xx >= 0 && xx < Wp) {
    const short8* s = (const short8*)src;
    size_t base = ((size_t)(b * H + 2 * yy) * W + 2 * xx) * n8 + v;
    short8 a0 = s[base], a1 = s[base + n8];
    short8 a2 = s[base + (size_t)W * n8], a3 = s[base + (size_t)W * n8 + n8];
    #pragma unroll
    for (int e = 0; e < 8; ++e) {  // post-relu bf16 >= 0: int max == float max
      unsigned short m0 = (unsigned short)a0[e], m1 = (unsigned short)a1[e];
      unsigned short m2 = (unsigned short)a2[e], m3 = (unsigned short)a3[e];
      unsigned short m = m0 > m1 ? m0 : m1;
      unsigned short n = m2 > m3 ? m2 : m3;
      outv[e] = (short)(m > n ? m : n);
    }
  }
  ((short8*)dst)[(size_t)row * (9 * n8) + tap * n8 + v] = outv;
}

// ---------------- prep: weight reorders + wuv + out zero + Fe coords + sen rows ----------------
__global__ void prep_kernel(const float* __restrict__ w2, const float* __restrict__ w3,
                            const float* __restrict__ w4, const float* __restrict__ g1w,
                            const float* __restrict__ sen, float* __restrict__ outz,
                            bf16* __restrict__ w2r, bf16* __restrict__ w3r,
                            bf16* __restrict__ w4r, bf16* __restrict__ wuv,
                            bf16* __restrict__ Fe) {
  const int S1 = 73728, S2 = S1 + 294912, S3 = S2 + 1179648, S4 = S3 + 442368,
            S5 = S4 + 12288, S6 = S5 + 24576, S7 = S6 + 36864;
  int i = blockIdx.x * 256 + threadIdx.x;
  if (i < S1) {  // w2r: OC=128 IC=64
    int j = i, K = 576, IC = 64;
    int oc = j / K, r = j - oc * K, tap = r / IC, ic = r - tap * IC;
    w2r[j] = f2b(w2[((size_t)oc * IC + ic) * 9 + tap]);
  } else if (i < S2) {  // w3r: OC=256 IC=128
    int j = i - S1, K = 1152, IC = 128;
    int oc = j / K, r = j - oc * K, tap = r / IC, ic = r - tap * IC;
    w3r[j] = f2b(w3[((size_t)oc * IC + ic) * 9 + tap]);
  } else if (i < S3) {  // w4r: OC=512 IC=256
    int j = i - S2, K = 2304, IC = 256;
    int oc = j / K, r = j - oc * K, tap = r / IC, ic = r - tap * IC;
    w4r[j] = f2b(w4[((size_t)oc * IC + ic) * 9 + tap]);
  } else if (i < S4) {  // wuv[768][576]: [A^T ; Bm^T ; Cm^T], K-padded
    int j = i - S3;
    int n = j / 576, c = j - n * 576;
    float val = 0.f;
    if (n < 256)      { if (c < 514) val = g1w[(size_t)c * 256 + n]; }
    else if (n < 512) { if (c < 514) val = g1w[(size_t)(514 + c) * 256 + (n - 256)]; }
    else              { if (c < 384) val = g1w[(size_t)(1028 + c) * 256 + (n - 512)]; }
    wuv[j] = f2b(val);
  } else if (i < S5) {  // zero output accumulator (d_out)
    outz[i - S4] = 0.f;
  } else if (i < S6) {  // Fe rows 0..383, cols 512..575: coords + pad
    int j = i - S5;
    int r = j >> 6, cc = j & 63;
    int p = r % 96;
    float val = 0.f;
    if (cc == 0) val = -1.0f + 2.0f * (float)(p / 8) / 11.0f;
    else if (cc == 1) val = -1.0f + 2.0f * (float)(p % 8) / 7.0f;
    Fe[(size_t)r * 576 + 512 + cc] = f2b(val);
  } else if (i < S7) {  // Fe rows 384..447: sen rows (b<4) + zeros
    int j = i - S6;
    int r = j / 576, c = j - r * 576;
    float val = (r < 4 && c < 384) ? sen[r * 384 + c] : 0.f;
    Fe[(size_t)(384 + r) * 576 + c] = f2b(val);
  }
}

// ---------------- combined f32->bf16 transposes: g2w(256x256)->w2t, g3w(256x3072)->w3t ----------------
__global__ void transpose2_kernel(const float* __restrict__ g2w, const float* __restrict__ g3w,
                                  bf16* __restrict__ w2t, bf16* __restrict__ w3t) {
  __shared__ bf16 t[32][33];
  int bid = blockIdx.x;
  const float* in;
  bf16* out;
  int R, C, c0, r0;
  if (bid < 64) { in = g2w; out = w2t; R = 256; C = 256; c0 = (bid & 7) * 32; r0 = (bid >> 3) * 32; }
  else { int b2 = bid - 64; in = g3w; out = w3t; R = 256; C = 3072; c0 = (b2 % 96) * 32; r0 = (b2 / 96) * 32; }
  int x = threadIdx.x & 31, y = threadIdx.x >> 5;
  for (int yy = y; yy < 32; yy += 8) {
    int r = r0 + yy, c = c0 + x;
    if (r < R && c < C) t[yy][x] = f2b(in[(size_t)r * C + c]);
  }
  __syncthreads();
  for (int yy = y; yy < 32; yy += 8) {
    int c = c0 + yy, r = r0 + x;
    if (r < R && c < C) out[(size_t)c * R + r] = t[x][yy];
  }
}

// ---------------- 64x64-tile GEMM, glds staging, for small/skinny GEMMs ----------------
// A[M][K]bf16, Wt[N][K]bf16. mode 0: outb=relu(acc+bias) bf16 (ldout); mode 2: outf=acc f32.
__launch_bounds__(256)
__global__ void gemm64_kernel(const bf16* __restrict__ A, const bf16* __restrict__ Wt,
                              const float* __restrict__ bias, bf16* __restrict__ outb,
                              float* __restrict__ outf, int K, int ldout, int mode) {
  int m0 = blockIdx.y * 64, n0 = blockIdx.x * 64;
  __shared__ __align__(16) short A_lds[64 * 64];
  __shared__ __align__(16) short B_lds[64 * 64];
  int tid = threadIdx.x, w = tid >> 6, l = tid & 63;
  int quad = l >> 4, l16 = l & 15;
  f32x4 acc[4];
  #pragma unroll
  for (int nt = 0; nt < 4; ++nt)
    #pragma unroll
    for (int e = 0; e < 4; ++e) acc[nt][e] = 0.f;

  // staging: instr (w,i): phys chunk c = w*128 + i*64 + l; row=c>>3=w*16+i*8+(l>>3); holds kl=(l&7)^(l>>3)
  int lrow = l >> 3;
  int c_sw = (l & 7) ^ lrow;
  const bf16* ag = A + (size_t)(m0 + w * 16 + lrow) * K + c_sw * 8;
  const bf16* bg = Wt + (size_t)(n0 + w * 16 + lrow) * K + c_sw * 8;
  short* al = A_lds + ((size_t)w * 128 + l) * 8;
  short* bl = B_lds + ((size_t)w * 128 + l) * 8;

  for (int kc = 0; kc < K; kc += 64) {
    if (kc) __syncthreads();
    #pragma unroll
    for (int i = 0; i < 2; ++i) {
      gload_lds16(ag + kc + (size_t)i * 8 * K, al + i * 512);
      gload_lds16(bg + kc + (size_t)i * 8 * K, bl + i * 512);
    }
    __syncthreads();
    #pragma unroll
    for (int ks = 0; ks < 64; ks += 32) {
      int cb = (ks >> 3) + quad;
      int mr = w * 16 + l16;
      short8 af = *(const short8*)&A_lds[mr * 64 + ((cb ^ (mr & 7)) * 8)];
      #pragma unroll
      for (int nt = 0; nt < 4; ++nt) {
        int nr = nt * 16 + l16;
        short8 bf = *(const short8*)&B_lds[nr * 64 + ((cb ^ (nr & 7)) * 8)];
        acc[nt] = __builtin_amdgcn_mfma_f32_16x16x32_bf16(af, bf, acc[nt], 0, 0, 0);
      }
    }
  }
  #pragma unroll
  for (int nt = 0; nt < 4; ++nt) {
    int gcol = n0 + nt * 16 + l16;
    float bv = (mode == 0) ? bias[gcol] : 0.f;
    #pragma unroll
    for (int r = 0; r < 4; ++r) {
      int grow = m0 + w * 16 + quad * 4 + r;
      if (mode == 0) outb[(size_t)grow * ldout + gcol] = f2b(fmaxf(acc[nt][r] + bv, 0.f));
      else           outf[(size_t)grow * ldout + gcol] = acc[nt][r];
    }
  }
}

// ---------------- GEMM2: h2 = relu(h1 @ W2 + b2); h1 formed on the fly (vectorized) ----------------
__launch_bounds__(256)
__global__ void gemm2_kernel(const float* __restrict__ uvws, const float* __restrict__ g1b,
                             const bf16* __restrict__ w2t, const float* __restrict__ g2b,
                             bf16* __restrict__ h2) {
  int b = blockIdx.z;
  int m0 = blockIdx.y * 128;
  int n0 = blockIdx.x * 128;
  __shared__ __align__(16) short A_lds[128 * 64];
  __shared__ __align__(16) short B_lds[128 * 64];
  __shared__ __align__(16) float wsl[256];
  int tid = threadIdx.x, w = tid >> 6, l = tid & 63;
  int quad = l >> 4, l16 = l & 15;
  int mw = (w >> 1) * 64, nw = (w & 1) * 64;
  f32x4 acc[4][4];
  #pragma unroll
  for (int i = 0; i < 4; ++i)
    #pragma unroll
    for (int j = 0; j < 4; ++j)
      #pragma unroll
      for (int e = 0; e < 4; ++e) acc[i][j][e] = 0.f;

  // ws (+bias g1b) for this batch into LDS
  wsl[tid] = uvws[(size_t)(384 + b) * 768 + 512 + tid] + g1b[tid];

  // B staging via glds (w2t, K=256), same swizzle as gemm3
  int lrow = l >> 3;
  int c_sw = (l & 7) ^ lrow;
  const bf16* bg = w2t + (size_t)(n0 + w * 32 + lrow) * 256 + c_sw * 8;
  short* bl = B_lds + ((size_t)w * 256 + l) * 8;

  // A source: h1 row m = i*96+j -> u[b,j] + v[b,i] + ws[b]
  int row = tid >> 1, ks0 = (tid & 1) * 32;
  int m = m0 + row;
  int i_idx = m / 96, j_idx = m - i_idx * 96;
  const float* up = uvws + (size_t)(b * 96 + j_idx) * 768 + ks0;
  const float* vp = uvws + (size_t)(b * 96 + i_idx) * 768 + 256 + ks0;
  __syncthreads();  // wsl ready

  for (int kc = 0; kc < 256; kc += 64) {
    if (kc) __syncthreads();
    #pragma unroll
    for (int i = 0; i < 4; ++i)
      gload_lds16(bg + kc + (size_t)i * 8 * 256, bl + i * 512);
    {
      const float4* u4 = (const float4*)(up + kc);
      const float4* v4 = (const float4*)(vp + kc);
      const float4* w4 = (const float4*)&wsl[kc + ks0];
      #pragma unroll
      for (int ch = 0; ch < 4; ++ch) {
        short8 pack;
        #pragma unroll
        for (int q = 0; q < 2; ++q) {
          float4 uu = u4[ch * 2 + q], vv = v4[ch * 2 + q], ww = w4[ch * 2 + q];
          pack[q * 4 + 0] = fb(uu.x + vv.x + ww.x);
          pack[q * 4 + 1] = fb(uu.y + vv.y + ww.y);
          pack[q * 4 + 2] = fb(uu.z + vv.z + ww.z);
          pack[q * 4 + 3] = fb(uu.w + vv.w + ww.w);
        }
        int lc = (ks0 >> 3) + ch;
        *(short8*)&A_lds[row * 64 + ((lc ^ (row & 7)) * 8)] = pack;
      }
    }
    __syncthreads();
    #pragma unroll
    for (int ks = 0; ks < 64; ks += 32) {
      int cb = (ks >> 3) + quad;
      short8 af[4], bfr[4];
      #pragma unroll
      for (int mt = 0; mt < 4; ++mt) {
        int mr = mw + mt * 16 + l16;
        af[mt] = *(const short8*)&A_lds[mr * 64 + ((cb ^ (mr & 7)) * 8)];
      }
      #pragma unroll
      for (int nt = 0; nt < 4; ++nt) {
        int nr = nw + nt * 16 + l16;
        bfr[nt] = *(const short8*)&B_lds[nr * 64 + ((cb ^ (nr & 7)) * 8)];
      }
      #pragma unroll
      for (int mt = 0; mt < 4; ++mt)
        #pragma unroll
        for (int nt = 0; nt < 4; ++nt)
          acc[mt][nt] = __builtin_amdgcn_mfma_f32_16x16x32_bf16(af[mt], bfr[nt], acc[mt][nt], 0, 0, 0);
    }
  }
  bf16* h2b = h2 + (size_t)b * 9216 * 256;
  #pragma unroll
  for (int nt = 0; nt < 4; ++nt) {
    int gcol = n0 + nw + nt * 16 + l16;
    float bias = g2b[gcol];
    #pragma unroll
    for (int mt = 0; mt < 4; ++mt) {
      #pragma unroll
      for (int r = 0; r < 4; ++r) {
        int grow = m0 + mw + mt * 16 + quad * 4 + r;
        h2b[(size_t)grow * 256 + gcol] = f2b(fmaxf(acc[mt][nt][r] + bias, 0.f));
      }
    }
  }
}

// ---------------- GEMM3 + relu + pair-sum, glds staging, XCD-swizzled grid ----------------
__launch_bounds__(256)
__global__ void gemm3_kernel(const bf16* __restrict__ h2, const bf16* __restrict__ w3t,
                             const float* __restrict__ g3b, float* __restrict__ phi) {
  // flat grid 6912 = 8(xcd) x 288(mb) x 24(n); same-mb blocks land 8 apart -> same XCD
  int g = blockIdx.x;
  int x = g & 7, s = g >> 3;
  int grp = s / 24;
  int nIdx = s - grp * 24;
  int mb = grp * 8 + x;
  int b = mb / 72;
  int m0 = (mb - b * 72) * 128;
  int n0 = nIdx * 128;
  __shared__ __align__(16) short A_lds[128 * 64];
  __shared__ __align__(16) short B_lds[128 * 64];
  int tid = threadIdx.x, w = tid >> 6, l = tid & 63;
  int quad = l >> 4, l16 = l & 15;
  int mw = (w >> 1) * 64, nw = (w & 1) * 64;
  f32x4 acc[4][4];
  #pragma unroll
  for (int i = 0; i < 4; ++i)
    #pragma unroll
    for (int j = 0; j < 4; ++j)
      #pragma unroll
      for (int e = 0; e < 4; ++e) acc[i][j][e] = 0.f;

  const int K = 256;
  int lrow = l >> 3;
  int c_sw = (l & 7) ^ lrow;
  const bf16* ag = h2 + (size_t)(b * 9216 + m0 + w * 32 + lrow) * K + c_sw * 8;
  const bf16* bg = w3t + (size_t)(n0 + w * 32 + lrow) * K + c_sw * 8;
  short* al = A_lds + ((size_t)w * 256 + l) * 8;
  short* bl = B_lds + ((size_t)w * 256 + l) * 8;

  for (int kc = 0; kc < K; kc += 64) {
    if (kc) __syncthreads();
    #pragma unroll
    for (int i = 0; i < 4; ++i) {
      gload_lds16(ag + kc + (size_t)i * 8 * K, al + i * 512);
      gload_lds16(bg + kc + (size_t)i * 8 * K, bl + i * 512);
    }
    __syncthreads();
    #pragma unroll
    for (int ks = 0; ks < 64; ks += 32) {
      int cb = (ks >> 3) + quad;
      short8 af[4], bfr[4];
      #pragma unroll
      for (int mt = 0; mt < 4; ++mt) {
        int mr = mw + mt * 16 + l16;
        af[mt] = *(const short8*)&A_lds[mr * 64 + ((cb ^ (mr & 7)) * 8)];
      }
      #pragma unroll
      for (int nt = 0; nt < 4; ++nt) {
        int nr = nw + nt * 16 + l16;
        bfr[nt] = *(const short8*)&B_lds[nr * 64 + ((cb ^ (nr & 7)) * 8)];
      }
      #pragma unroll
      for (int mt = 0; mt < 4; ++mt)
        #pragma unroll
        for (int nt = 0; nt < 4; ++nt)
          acc[mt][nt] = __builtin_amdgcn_mfma_f32_16x16x32_bf16(af[mt], bfr[nt], acc[mt][nt], 0, 0, 0);
    }
  }
  #pragma unroll
  for (int nt = 0; nt < 4; ++nt) {
    int gcol = n0 + nw + nt * 16 + l16;
    float bias = g3b[gcol];
    float s2 = 0.f;
    #pragma unroll
    for (int mt = 0; mt < 4; ++mt)
      #pragma unroll
      for (int r = 0; r < 4; ++r)
        s2 += fmaxf(acc[mt][nt][r] + bias, 0.f);
    s2 += __shfl_xor(s2, 16, 64);
    s2 += __shfl_xor(s2, 32, 64);
    if (quad == 0) atomicAdd(&phi[b * 3072 + gcol], s2);
  }
}

extern "C" void kernel_launch(void* const* d_in, const int* in_sizes, int n_in,
                              void* d_out, int out_size, void* d_ws, size_t ws_size,
                              hipStream_t stream) {
  const float* x   = (const float*)d_in[0];
  const float* sen = (const float*)d_in[1];
  const float* w1  = (const float*)d_in[2];
  const float* b1  = (const float*)d_in[3];
  const float* w2  = (const float*)d_in[4];
  const float* b2  = (const float*)d_in[5];
  const float* w3  = (const float*)d_in[6];
  const float* b3  = (const float*)d_in[7];
  const float* w4  = (const float*)d_in[8];
  const float* b4  = (const float*)d_in[9];
  const float* g1w = (const float*)d_in[10];
  const float* g1b = (const float*)d_in[11];
  const float* g2w = (const float*)d_in[12];
  const float* g2b = (const float*)d_in[13];
  const float* g3w = (const float*)d_in[14];
  const float* g3b = (const float*)d_in[15];
  float* out = (float*)d_out;

  char* wsp = (char*)d_ws;
  size_t off = 0;
  auto alloc = [&](size_t bytes) {
    char* p = wsp + off;
    off += (bytes + 255) & ~(size_t)255;
    return (void*)p;
  };
  bf16* e1   = (bf16*)alloc((size_t)4 * 6144 * 64 * 2);
  bf16* col2 = (bf16*)alloc((size_t)6144 * 576 * 2);
  bf16* e2   = (bf16*)alloc((size_t)6144 * 128 * 2);
  bf16* col3 = (bf16*)alloc((size_t)1536 * 1152 * 2);
  bf16* e3   = (bf16*)alloc((size_t)1536 * 256 * 2);
  bf16* col4 = (bf16*)alloc((size_t)384 * 2304 * 2);
  bf16* Fe   = (bf16*)alloc((size_t)448 * 576 * 2);        // [F|coords|pad ; sen rows]
  bf16* wuv  = (bf16*)alloc((size_t)768 * 576 * 2);        // [A^T ; Bm^T ; Cm^T]
  float* uvws = (float*)alloc((size_t)448 * 768 * 4);      // [u|v|ws'] f32
  bf16* w2r  = (bf16*)alloc((size_t)128 * 576 * 2);
  bf16* w3r  = (bf16*)alloc((size_t)256 * 1152 * 2);
  bf16* w4r  = (bf16*)alloc((size_t)512 * 2304 * 2);
  bf16* w2t  = (bf16*)alloc((size_t)256 * 256 * 2);
  bf16* w3t  = (bf16*)alloc((size_t)3072 * 256 * 2);
  bf16* h2   = (bf16*)alloc((size_t)4 * 9216 * 256 * 2);

  // prep (zeroes d_out; input-only deps)
  prep_kernel<<<dim3(8064), 256, 0, stream>>>(w2, w3, w4, g1w, sen, out, w2r, w3r, w4r, wuv, Fe);
  transpose2_kernel<<<dim3(832), 256, 0, stream>>>(g2w, g3w, w2t, w3t);

  // encoder
  conv1_nhwc_kernel<<<dim3(6144), 256, 0, stream>>>(x, w1, b1, e1);
  pool_im2col_kernel<<<dim3(1728), 256, 0, stream>>>(e1, col2, 64, 96, 64);
  gemm64_kernel<<<dim3(2, 96), 256, 0, stream>>>(col2, w2r, b2, e2, nullptr, 576, 128, 0);
  pool_im2col_kernel<<<dim3(864), 256, 0, stream>>>(e2, col3, 32, 48, 128);
  gemm64_kernel<<<dim3(4, 24), 256, 0, stream>>>(col3, w3r, b3, e3, nullptr, 1152, 256, 0);
  pool_im2col_kernel<<<dim3(432), 256, 0, stream>>>(e3, col4, 16, 24, 256);
  gemm64_kernel<<<dim3(8, 6), 256, 0, stream>>>(col4, w4r, b4, Fe, nullptr, 2304, 576, 0);

  // head: u,v,ws in one GEMM (M=448, N=768, K=576)
  gemm64_kernel<<<dim3(12, 7), 256, 0, stream>>>(Fe, wuv, nullptr, nullptr, uvws, 576, 768, 2);
  gemm2_kernel<<<dim3(2, 72, 4), 256, 0, stream>>>(uvws, g1b, w2t, g2b, h2);
  gemm3_kernel<<<dim3(6912), 256, 0, stream>>>(h2, w3t, g3b, out);
}

// Round 6
// 248.059 us; speedup vs baseline: 5.2015x; 1.1414x over previous
//
#include <hip/hip_runtime.h>
#include <hip/hip_bf16.h>

using bf16 = __hip_bfloat16;
typedef __attribute__((ext_vector_type(8))) short short8;
typedef __attribute__((ext_vector_type(4))) float f32x4;

static __device__ __forceinline__ bf16 f2b(float x) { return __float2bfloat16(x); }
static __device__ __forceinline__ float b2f(bf16 x) { return __bfloat162float(x); }
static __device__ __forceinline__ short fb(float x) {
  bf16 h = __float2bfloat16(fmaxf(x, 0.f));
  return *(short*)&h;
}

// async global->LDS, 16B per lane. Global src address is PER-LANE; LDS dest = uniform base + lane*16.
static __device__ __forceinline__ void gload_lds16(const void* g, void* l) {
  auto gp = (const __attribute__((address_space(1))) unsigned int*)g;
  auto lp = (__attribute__((address_space(3))) unsigned int*)l;
  __builtin_amdgcn_global_load_lds(gp, lp, 16, 0, 0);
}

// ---------------- conv1 + maxpool fused: NCHW f32 -> pooled NHWC bf16 [4][32][48][64] ----------------
__global__ void conv1pool_kernel(const float* __restrict__ x, const float* __restrict__ w,
                                 const float* __restrict__ bias, bf16* __restrict__ out) {
  const int H = 64, W = 96, HW = H * W;
  __shared__ float wl[27 * 64];
  int tid = threadIdx.x;
  for (int idx = tid; idx < 27 * 64; idx += 256) {
    int k = idx >> 6, oc_ = idx & 63;
    wl[idx] = w[oc_ * 27 + k];
  }
  __syncthreads();
  int oc = tid & 63;
  int pp = blockIdx.x * 4 + (tid >> 6);   // pooled pixel (b,yp,xp)
  int b = pp / 1536, rem = pp - b * 1536;
  int yp = rem / 48, xp = rem - yp * 48;
  int y0 = 2 * yp - 1, x0 = 2 * xp - 1;
  float win[3][4][4];
  #pragma unroll
  for (int ic = 0; ic < 3; ++ic) {
    const float* xsrc = x + ((size_t)b * 3 + ic) * HW;
    #pragma unroll
    for (int dy = 0; dy < 4; ++dy) {
      int yy = y0 + dy;
      #pragma unroll
      for (int dx = 0; dx < 4; ++dx) {
        int xx = x0 + dx;
        win[ic][dy][dx] = (yy >= 0 && yy < H && xx >= 0 && xx < W) ? xsrc[yy * W + xx] : 0.f;
      }
    }
  }
  float cmax = -1e30f;
  #pragma unroll
  for (int sy = 0; sy < 2; ++sy)
    #pragma unroll
    for (int sx = 0; sx < 2; ++sx) {
      float acc = 0.f;
      #pragma unroll
      for (int ic = 0; ic < 3; ++ic)
        #pragma unroll
        for (int ky = 0; ky < 3; ++ky)
          #pragma unroll
          for (int kx = 0; kx < 3; ++kx)
            acc += win[ic][sy + ky][sx + kx] * wl[(ic * 9 + ky * 3 + kx) * 64 + oc];
      cmax = fmaxf(cmax, acc);
    }
  out[(size_t)pp * 64 + oc] = f2b(fmaxf(cmax + bias[oc], 0.f));
}

// ---------------- prep: weight reorders + wuv + out zero + Fe coords + sen rows + zero buffer ----------------
__global__ void prep_kernel(const float* __restrict__ w2, const float* __restrict__ w3,
                            const float* __restrict__ w4, const float* __restrict__ g1w,
                            const float* __restrict__ sen, float* __restrict__ outz,
                            bf16* __restrict__ w2r, bf16* __restrict__ w3r,
                            bf16* __restrict__ w4r, bf16* __restrict__ wuv,
                            bf16* __restrict__ Fe, float* __restrict__ zb) {
  const int S1 = 73728, S2 = S1 + 294912, S3 = S2 + 1179648, S4 = S3 + 442368,
            S5 = S4 + 12288, S6 = S5 + 24576, S7 = S6 + 36864, S8 = S7 + 64;
  int i = blockIdx.x * 256 + threadIdx.x;
  if (i < S1) {  // w2r: OC=128 IC=64, [oc][tap*IC+ic]
    int j = i, K = 576, IC = 64;
    int oc = j / K, r = j - oc * K, tap = r / IC, ic = r - tap * IC;
    w2r[j] = f2b(w2[((size_t)oc * IC + ic) * 9 + tap]);
  } else if (i < S2) {  // w3r: OC=256 IC=128
    int j = i - S1, K = 1152, IC = 128;
    int oc = j / K, r = j - oc * K, tap = r / IC, ic = r - tap * IC;
    w3r[j] = f2b(w3[((size_t)oc * IC + ic) * 9 + tap]);
  } else if (i < S3) {  // w4r: OC=512 IC=256
    int j = i - S2, K = 2304, IC = 256;
    int oc = j / K, r = j - oc * K, tap = r / IC, ic = r - tap * IC;
    w4r[j] = f2b(w4[((size_t)oc * IC + ic) * 9 + tap]);
  } else if (i < S4) {  // wuv[768][576]: [A^T ; Bm^T ; Cm^T], K-padded
    int j = i - S3;
    int n = j / 576, c = j - n * 576;
    float val = 0.f;
    if (n < 256)      { if (c < 514) val = g1w[(size_t)c * 256 + n]; }
    else if (n < 512) { if (c < 514) val = g1w[(size_t)(514 + c) * 256 + (n - 256)]; }
    else              { if (c < 384) val = g1w[(size_t)(1028 + c) * 256 + (n - 512)]; }
    wuv[j] = f2b(val);
  } else if (i < S5) {  // zero output accumulator (d_out)
    outz[i - S4] = 0.f;
  } else if (i < S6) {  // Fe rows 0..383, cols 512..575: coords + pad
    int j = i - S5;
    int r = j >> 6, cc = j & 63;
    int p = r % 96;
    float val = 0.f;
    if (cc == 0) val = -1.0f + 2.0f * (float)(p / 8) / 11.0f;
    else if (cc == 1) val = -1.0f + 2.0f * (float)(p % 8) / 7.0f;
    Fe[(size_t)r * 576 + 512 + cc] = f2b(val);
  } else if (i < S7) {  // Fe rows 384..447: sen rows (b<4) + zeros
    int j = i - S6;
    int r = j / 576, c = j - r * 576;
    float val = (r < 4 && c < 384) ? sen[r * 384 + c] : 0.f;
    Fe[(size_t)(384 + r) * 576 + c] = f2b(val);
  } else if (i < S8) {  // zero buffer for OOB im2col lanes
    zb[i - S7] = 0.f;
  }
}

// ---------------- combined f32->bf16 transposes: g2w(256x256)->w2t, g3w(256x3072)->w3t ----------------
__global__ void transpose2_kernel(const float* __restrict__ g2w, const float* __restrict__ g3w,
                                  bf16* __restrict__ w2t, bf16* __restrict__ w3t) {
  __shared__ bf16 t[32][33];
  int bid = blockIdx.x;
  const float* in;
  bf16* out;
  int R, C, c0, r0;
  if (bid < 64) { in = g2w; out = w2t; R = 256; C = 256; c0 = (bid & 7) * 32; r0 = (bid >> 3) * 32; }
  else { int b2 = bid - 64; in = g3w; out = w3t; R = 256; C = 3072; c0 = (b2 % 96) * 32; r0 = (b2 / 96) * 32; }
  int x = threadIdx.x & 31, y = threadIdx.x >> 5;
  for (int yy = y; yy < 32; yy += 8) {
    int r = r0 + yy, c = c0 + x;
    if (r < R && c < C) t[yy][x] = f2b(in[(size_t)r * C + c]);
  }
  __syncthreads();
  for (int yy = y; yy < 32; yy += 8) {
    int c = c0 + yy, r = r0 + x;
    if (r < R && c < C) out[(size_t)c * R + r] = t[x][yy];
  }
}

// ---------------- conv GEMM: implicit im2col (glds per-lane addr) + optional fused pool epilogue ----
// A rows: POOL -> pool-group-major pre-pool pixels; else plain (b,y,x). K = 9<<CBITS.
template <int CBITS, bool POOL>
__launch_bounds__(256)
__global__ void gemm_conv_kernel(const bf16* __restrict__ pin, const bf16* __restrict__ Wt,
                                 const float* __restrict__ bias, bf16* __restrict__ outb,
                                 const bf16* __restrict__ zbuf,
                                 int Hi, int Wi, int N, int ldout) {
  const int C = 1 << CBITS;
  const int K = 9 << CBITS;
  int m0 = blockIdx.y * 64, n0 = blockIdx.x * 64;
  __shared__ __align__(16) short A_lds[64 * 64];
  __shared__ __align__(16) short B_lds[64 * 64];
  int tid = threadIdx.x, w = tid >> 6, l = tid & 63;
  int quad = l >> 4, l16 = l & 15;
  f32x4 acc[4];
  #pragma unroll
  for (int nt = 0; nt < 4; ++nt)
    #pragma unroll
    for (int e = 0; e < 4; ++e) acc[nt][e] = 0.f;

  int lrow = l >> 3;
  int c_sw = (l & 7) ^ lrow;
  // hoisted row -> (b, y, x) decode for the two staged rows
  int ybase[2], xbase[2], bidx[2];
  #pragma unroll
  for (int i = 0; i < 2; ++i) {
    int row = m0 + w * 16 + i * 8 + lrow;
    if (POOL) {
      int pg = row >> 2, sub = row & 3;
      int Wh = Wi >> 1, HW2 = (Hi >> 1) * Wh;
      int b = pg / HW2, rem = pg - b * HW2;
      int py = rem / Wh, px = rem - py * Wh;
      bidx[i] = b; ybase[i] = 2 * py + (sub >> 1); xbase[i] = 2 * px + (sub & 1);
    } else {
      int HW = Hi * Wi;
      int b = row / HW, pix = row - b * HW;
      int yy = pix / Wi;
      bidx[i] = b; ybase[i] = yy; xbase[i] = pix - yy * Wi;
    }
  }
  const bf16* bg = Wt + (size_t)(n0 + w * 16 + lrow) * K + c_sw * 8;
  short* al = A_lds + ((size_t)w * 128 + l) * 8;
  short* bl = B_lds + ((size_t)w * 128 + l) * 8;

  for (int kc = 0; kc < K; kc += 64) {
    if (kc) __syncthreads();
    int colt = kc + c_sw * 8;
    int tap = colt >> CBITS, cc = colt & (C - 1);
    int ty = tap / 3, tx = tap - 3 * ty;
    #pragma unroll
    for (int i = 0; i < 2; ++i) {
      int yy = ybase[i] + ty - 1, xx = xbase[i] + tx - 1;
      const bf16* asrc = (yy >= 0 && yy < Hi && xx >= 0 && xx < Wi)
          ? pin + ((((size_t)(bidx[i] * Hi + yy)) * Wi + xx) << CBITS) + cc
          : zbuf;
      gload_lds16(asrc, al + i * 512);
      gload_lds16(bg + kc + (size_t)i * 8 * K, bl + i * 512);
    }
    __syncthreads();
    #pragma unroll
    for (int ks = 0; ks < 64; ks += 32) {
      int cb = (ks >> 3) + quad;
      int mr = w * 16 + l16;
      short8 af = *(const short8*)&A_lds[mr * 64 + ((cb ^ (mr & 7)) * 8)];
      #pragma unroll
      for (int nt = 0; nt < 4; ++nt) {
        int nr = nt * 16 + l16;
        short8 bf = *(const short8*)&B_lds[nr * 64 + ((cb ^ (nr & 7)) * 8)];
        acc[nt] = __builtin_amdgcn_mfma_f32_16x16x32_bf16(af, bf, acc[nt], 0, 0, 0);
      }
    }
  }
  if (POOL) {
    // lane's 4 acc rows (quad*4+r) == one pool group (all offsets multiples of 4)
    int pg = (m0 + w * 16 + quad * 4) >> 2;
    #pragma unroll
    for (int nt = 0; nt < 4; ++nt) {
      int gcol = n0 + nt * 16 + l16;
      float bv = bias[gcol];
      float m = fmaxf(fmaxf(acc[nt][0], acc[nt][1]), fmaxf(acc[nt][2], acc[nt][3]));
      outb[(size_t)pg * N + gcol] = f2b(fmaxf(m + bv, 0.f));
    }
  } else {
    #pragma unroll
    for (int nt = 0; nt < 4; ++nt) {
      int gcol = n0 + nt * 16 + l16;
      float bv = bias[gcol];
      #pragma unroll
      for (int r = 0; r < 4; ++r) {
        int grow = m0 + w * 16 + quad * 4 + r;
        outb[(size_t)grow * ldout + gcol] = f2b(fmaxf(acc[nt][r] + bv, 0.f));
      }
    }
  }
}

// ---------------- 64x64-tile GEMM, glds staging (used for uv head GEMM) ----------------
__launch_bounds__(256)
__global__ void gemm64_kernel(const bf16* __restrict__ A, const bf16* __restrict__ Wt,
                              float* __restrict__ outf, int K, int ldout) {
  int m0 = blockIdx.y * 64, n0 = blockIdx.x * 64;
  __shared__ __align__(16) short A_lds[64 * 64];
  __shared__ __align__(16) short B_lds[64 * 64];
  int tid = threadIdx.x, w = tid >> 6, l = tid & 63;
  int quad = l >> 4, l16 = l & 15;
  f32x4 acc[4];
  #pragma unroll
  for (int nt = 0; nt < 4; ++nt)
    #pragma unroll
    for (int e = 0; e < 4; ++e) acc[nt][e] = 0.f;

  int lrow = l >> 3;
  int c_sw = (l & 7) ^ lrow;
  const bf16* ag = A + (size_t)(m0 + w * 16 + lrow) * K + c_sw * 8;
  const bf16* bg = Wt + (size_t)(n0 + w * 16 + lrow) * K + c_sw * 8;
  short* al = A_lds + ((size_t)w * 128 + l) * 8;
  short* bl = B_lds + ((size_t)w * 128 + l) * 8;

  for (int kc = 0; kc < K; kc += 64) {
    if (kc) __syncthreads();
    #pragma unroll
    for (int i = 0; i < 2; ++i) {
      gload_lds16(ag + kc + (size_t)i * 8 * K, al + i * 512);
      gload_lds16(bg + kc + (size_t)i * 8 * K, bl + i * 512);
    }
    __syncthreads();
    #pragma unroll
    for (int ks = 0; ks < 64; ks += 32) {
      int cb = (ks >> 3) + quad;
      int mr = w * 16 + l16;
      short8 af = *(const short8*)&A_lds[mr * 64 + ((cb ^ (mr & 7)) * 8)];
      #pragma unroll
      for (int nt = 0; nt < 4; ++nt) {
        int nr = nt * 16 + l16;
        short8 bf = *(const short8*)&B_lds[nr * 64 + ((cb ^ (nr & 7)) * 8)];
        acc[nt] = __builtin_amdgcn_mfma_f32_16x16x32_bf16(af, bf, acc[nt], 0, 0, 0);
      }
    }
  }
  #pragma unroll
  for (int nt = 0; nt < 4; ++nt) {
    int gcol = n0 + nt * 16 + l16;
    #pragma unroll
    for (int r = 0; r < 4; ++r) {
      int grow = m0 + w * 16 + quad * 4 + r;
      outf[(size_t)grow * ldout + gcol] = acc[nt][r];
    }
  }
}

// ---------------- GEMM2: h2 = relu(h1 @ W2 + b2); h1 formed on the fly (vectorized) ----------------
__launch_bounds__(256)
__global__ void gemm2_kernel(const float* __restrict__ uvws, const float* __restrict__ g1b,
                             const bf16* __restrict__ w2t, const float* __restrict__ g2b,
                             bf16* __restrict__ h2) {
  int b = blockIdx.z;
  int m0 = blockIdx.y * 128;
  int n0 = blockIdx.x * 128;
  __shared__ __align__(16) short A_lds[128 * 64];
  __shared__ __align__(16) short B_lds[128 * 64];
  __shared__ __align__(16) float wsl[256];
  int tid = threadIdx.x, w = tid >> 6, l = tid & 63;
  int quad = l >> 4, l16 = l & 15;
  int mw = (w >> 1) * 64, nw = (w & 1) * 64;
  f32x4 acc[4][4];
  #pragma unroll
  for (int i = 0; i < 4; ++i)
    #pragma unroll
    for (int j = 0; j < 4; ++j)
      #pragma unroll
      for (int e = 0; e < 4; ++e) acc[i][j][e] = 0.f;

  wsl[tid] = uvws[(size_t)(384 + b) * 768 + 512 + tid] + g1b[tid];

  int lrow = l >> 3;
  int c_sw = (l & 7) ^ lrow;
  const bf16* bg = w2t + (size_t)(n0 + w * 32 + lrow) * 256 + c_sw * 8;
  short* bl = B_lds + ((size_t)w * 256 + l) * 8;

  int row = tid >> 1, ks0 = (tid & 1) * 32;
  int m = m0 + row;
  int i_idx = m / 96, j_idx = m - i_idx * 96;
  const float* up = uvws + (size_t)(b * 96 + j_idx) * 768 + ks0;
  const float* vp = uvws + (size_t)(b * 96 + i_idx) * 768 + 256 + ks0;
  __syncthreads();

  for (int kc = 0; kc < 256; kc += 64) {
    if (kc) __syncthreads();
    #pragma unroll
    for (int i = 0; i < 4; ++i)
      gload_lds16(bg + kc + (size_t)i * 8 * 256, bl + i * 512);
    {
      const float4* u4 = (const float4*)(up + kc);
      const float4* v4 = (const float4*)(vp + kc);
      const float4* w4 = (const float4*)&wsl[kc + ks0];
      #pragma unroll
      for (int ch = 0; ch < 4; ++ch) {
        short8 pack;
        #pragma unroll
        for (int q = 0; q < 2; ++q) {
          float4 uu = u4[ch * 2 + q], vv = v4[ch * 2 + q], ww = w4[ch * 2 + q];
          pack[q * 4 + 0] = fb(uu.x + vv.x + ww.x);
          pack[q * 4 + 1] = fb(uu.y + vv.y + ww.y);
          pack[q * 4 + 2] = fb(uu.z + vv.z + ww.z);
          pack[q * 4 + 3] = fb(uu.w + vv.w + ww.w);
        }
        int lc = (ks0 >> 3) + ch;
        *(short8*)&A_lds[row * 64 + ((lc ^ (row & 7)) * 8)] = pack;
      }
    }
    __syncthreads();
    #pragma unroll
    for (int ks = 0; ks < 64; ks += 32) {
      int cb = (ks >> 3) + quad;
      short8 af[4], bfr[4];
      #pragma unroll
      for (int mt = 0; mt < 4; ++mt) {
        int mr = mw + mt * 16 + l16;
        af[mt] = *(const short8*)&A_lds[mr * 64 + ((cb ^ (mr & 7)) * 8)];
      }
      #pragma unroll
      for (int nt = 0; nt < 4; ++nt) {
        int nr = nw + nt * 16 + l16;
        bfr[nt] = *(const short8*)&B_lds[nr * 64 + ((cb ^ (nr & 7)) * 8)];
      }
      #pragma unroll
      for (int mt = 0; mt < 4; ++mt)
        #pragma unroll
        for (int nt = 0; nt < 4; ++nt)
          acc[mt][nt] = __builtin_amdgcn_mfma_f32_16x16x32_bf16(af[mt], bfr[nt], acc[mt][nt], 0, 0, 0);
    }
  }
  bf16* h2b = h2 + (size_t)b * 9216 * 256;
  #pragma unroll
  for (int nt = 0; nt < 4; ++nt) {
    int gcol = n0 + nw + nt * 16 + l16;
    float bias = g2b[gcol];
    #pragma unroll
    for (int mt = 0; mt < 4; ++mt) {
      #pragma unroll
      for (int r = 0; r < 4; ++r) {
        int grow = m0 + mw + mt * 16 + quad * 4 + r;
        h2b[(size_t)grow * 256 + gcol] = f2b(fmaxf(acc[mt][nt][r] + bias, 0.f));
      }
    }
  }
}

// ---------------- GEMM3 + relu + pair-sum, glds staging, XCD-swizzled grid ----------------
__launch_bounds__(256)
__global__ void gemm3_kernel(const bf16* __restrict__ h2, const bf16* __restrict__ w3t,
                             const float* __restrict__ g3b, float* __restrict__ phi) {
  int g = blockIdx.x;
  int x = g & 7, s = g >> 3;
  int grp = s / 24;
  int nIdx = s - grp * 24;
  int mb = grp * 8 + x;
  int b = mb / 72;
  int m0 = (mb - b * 72) * 128;
  int n0 = nIdx * 128;
  __shared__ __align__(16) short A_lds[128 * 64];
  __shared__ __align__(16) short B_lds[128 * 64];
  int tid = threadIdx.x, w = tid >> 6, l = tid & 63;
  int quad = l >> 4, l16 = l & 15;
  int mw = (w >> 1) * 64, nw = (w & 1) * 64;
  f32x4 acc[4][4];
  #pragma unroll
  for (int i = 0; i < 4; ++i)
    #pragma unroll
    for (int j = 0; j < 4; ++j)
      #pragma unroll
      for (int e = 0; e < 4; ++e) acc[i][j][e] = 0.f;

  const int K = 256;
  int lrow = l >> 3;
  int c_sw = (l & 7) ^ lrow;
  const bf16* ag = h2 + (size_t)(b * 9216 + m0 + w * 32 + lrow) * K + c_sw * 8;
  const bf16* bg = w3t + (size_t)(n0 + w * 32 + lrow) * K + c_sw * 8;
  short* al = A_lds + ((size_t)w * 256 + l) * 8;
  short* bl = B_lds + ((size_t)w * 256 + l) * 8;

  for (int kc = 0; kc < K; kc += 64) {
    if (kc) __syncthreads();
    #pragma unroll
    for (int i = 0; i < 4; ++i) {
      gload_lds16(ag + kc + (size_t)i * 8 * K, al + i * 512);
      gload_lds16(bg + kc + (size_t)i * 8 * K, bl + i * 512);
    }
    __syncthreads();
    #pragma unroll
    for (int ks = 0; ks < 64; ks += 32) {
      int cb = (ks >> 3) + quad;
      short8 af[4], bfr[4];
      #pragma unroll
      for (int mt = 0; mt < 4; ++mt) {
        int mr = mw + mt * 16 + l16;
        af[mt] = *(const short8*)&A_lds[mr * 64 + ((cb ^ (mr & 7)) * 8)];
      }
      #pragma unroll
      for (int nt = 0; nt < 4; ++nt) {
        int nr = nw + nt * 16 + l16;
        bfr[nt] = *(const short8*)&B_lds[nr * 64 + ((cb ^ (nr & 7)) * 8)];
      }
      #pragma unroll
      for (int mt = 0; mt < 4; ++mt)
        #pragma unroll
        for (int nt = 0; nt < 4; ++nt)
          acc[mt][nt] = __builtin_amdgcn_mfma_f32_16x16x32_bf16(af[mt], bfr[nt], acc[mt][nt], 0, 0, 0);
    }
  }
  #pragma unroll
  for (int nt = 0; nt < 4; ++nt) {
    int gcol = n0 + nw + nt * 16 + l16;
    float bias = g3b[gcol];
    float s2 = 0.f;
    #pragma unroll
    for (int mt = 0; mt < 4; ++mt)
      #pragma unroll
      for (int r = 0; r < 4; ++r)
        s2 += fmaxf(acc[mt][nt][r] + bias, 0.f);
    s2 += __shfl_xor(s2, 16, 64);
    s2 += __shfl_xor(s2, 32, 64);
    if (quad == 0) atomicAdd(&phi[b * 3072 + gcol], s2);
  }
}

extern "C" void kernel_launch(void* const* d_in, const int* in_sizes, int n_in,
                              void* d_out, int out_size, void* d_ws, size_t ws_size,
                              hipStream_t stream) {
  const float* x   = (const float*)d_in[0];
  const float* sen = (const float*)d_in[1];
  const float* w1  = (const float*)d_in[2];
  const float* b1  = (const float*)d_in[3];
  const float* w2  = (const float*)d_in[4];
  const float* b2  = (const float*)d_in[5];
  const float* w3  = (const float*)d_in[6];
  const float* b3  = (const float*)d_in[7];
  const float* w4  = (const float*)d_in[8];
  const float* b4  = (const float*)d_in[9];
  const float* g1w = (const float*)d_in[10];
  const float* g1b = (const float*)d_in[11];
  const float* g2w = (const float*)d_in[12];
  const float* g2b = (const float*)d_in[13];
  const float* g3w = (const float*)d_in[14];
  const float* g3b = (const float*)d_in[15];
  float* out = (float*)d_out;

  char* wsp = (char*)d_ws;
  size_t off = 0;
  auto alloc = [&](size_t bytes) {
    char* p = wsp + off;
    off += (bytes + 255) & ~(size_t)255;
    return (void*)p;
  };
  bf16* p1   = (bf16*)alloc((size_t)6144 * 64 * 2);        // pooled NHWC 4x32x48x64
  bf16* p2   = (bf16*)alloc((size_t)1536 * 128 * 2);       // 4x16x24x128
  bf16* p3   = (bf16*)alloc((size_t)384 * 256 * 2);        // 4x8x12x256
  bf16* Fe   = (bf16*)alloc((size_t)448 * 576 * 2);        // [F|coords|pad ; sen rows]
  bf16* wuv  = (bf16*)alloc((size_t)768 * 576 * 2);        // [A^T ; Bm^T ; Cm^T]
  float* uvws = (float*)alloc((size_t)448 * 768 * 4);      // [u|v|ws']
  bf16* w2r  = (bf16*)alloc((size_t)128 * 576 * 2);
  bf16* w3r  = (bf16*)alloc((size_t)256 * 1152 * 2);
  bf16* w4r  = (bf16*)alloc((size_t)512 * 2304 * 2);
  bf16* w2t  = (bf16*)alloc((size_t)256 * 256 * 2);
  bf16* w3t  = (bf16*)alloc((size_t)3072 * 256 * 2);
  bf16* h2   = (bf16*)alloc((size_t)4 * 9216 * 256 * 2);
  float* zbuf = (float*)alloc((size_t)256);                // OOB target for implicit im2col

  // prep (zeroes d_out + zbuf; input-only deps)
  prep_kernel<<<dim3(8065), 256, 0, stream>>>(w2, w3, w4, g1w, sen, out, w2r, w3r, w4r, wuv, Fe, zbuf);
  transpose2_kernel<<<dim3(832), 256, 0, stream>>>(g2w, g3w, w2t, w3t);

  // encoder: conv1+pool direct, then implicit-im2col conv GEMMs with fused pooling
  conv1pool_kernel<<<dim3(1536), 256, 0, stream>>>(x, w1, b1, p1);
  gemm_conv_kernel<6, true><<<dim3(2, 96), 256, 0, stream>>>(p1, w2r, b2, p2, (const bf16*)zbuf, 32, 48, 128, 128);
  gemm_conv_kernel<7, true><<<dim3(4, 24), 256, 0, stream>>>(p2, w3r, b3, p3, (const bf16*)zbuf, 16, 24, 256, 256);
  gemm_conv_kernel<8, false><<<dim3(8, 6), 256, 0, stream>>>(p3, w4r, b4, Fe, (const bf16*)zbuf, 8, 12, 512, 576);

  // head: u,v,ws in one GEMM (M=448, N=768, K=576)
  gemm64_kernel<<<dim3(12, 7), 256, 0, stream>>>(Fe, wuv, uvws, 576, 768);
  gemm2_kernel<<<dim3(2, 72, 4), 256, 0, stream>>>(uvws, g1b, w2t, g2b, h2);
  gemm3_kernel<<<dim3(6912), 256, 0, stream>>>(h2, w3t, g3b, out);
}